// Round 5
// baseline (14438.196 us; speedup 1.0000x reference)
//
#include <hip/hip_runtime.h>
#include <stdint.h>

#define B_SZ 128
#define SEQL 1024
#define EMB  64
#define HID  512
#define VOC  96
#define LDS_G 136
#define PKT  1536   // baseline kernel: 512 threads * 3 packets per parity

// Path-A stream geometry
#define CHUNK 34
#define NCHUNK 31
#define TU64 2048                        // u64 per (rg,t) = 16 KB
#define SLOT_U64 (CHUNK * TU64)          // 69632 u64 per (rg,chunk-slot)

typedef __attribute__((ext_vector_type(8))) short bf16x8;
typedef __attribute__((ext_vector_type(4))) float f32x4;

__device__ __forceinline__ float bf2f(ushort u) {
  union { uint32_t i; float f; } c; c.i = ((uint32_t)u) << 16; return c.f;
}
__device__ __forceinline__ ushort f2bf(float f) {
  union { float f; uint32_t i; } c; c.f = f;
  uint32_t u = c.i;
  return (ushort)((u + 0x7fffu + ((u >> 16) & 1u)) >> 16);
}
__device__ __forceinline__ float fast_tanh(float v) {
  float e = __expf(2.0f * v);
  return (e - 1.0f) * __builtin_amdgcn_rcpf(e + 1.0f);
}
__device__ __forceinline__ uint64_t pack3(ushort a, ushort b, ushort c, uint32_t tag) {
  return (uint64_t)a | ((uint64_t)b << 16) | ((uint64_t)c << 32) | ((uint64_t)tag << 48);
}
__device__ __forceinline__ uint64_t pload(const uint64_t* p) {
  return __hip_atomic_load((uint64_t*)p, __ATOMIC_RELAXED, __HIP_MEMORY_SCOPE_SYSTEM);
}
__device__ __forceinline__ void pstore(uint64_t* p, uint64_t v) {
  __hip_atomic_store(p, v, __ATOMIC_RELAXED, __HIP_MEMORY_SCOPE_SYSTEM);
}

// flags[0]=dtype mode (0 bf16 / 1 f32); flags[1]=x stride (1 int32 / 2 int64)
__global__ void detect_kernel(const ushort* __restrict__ emb_u16,
                              const int* __restrict__ x32, int* __restrict__ flags) {
  if (blockIdx.x != 0 || threadIdx.x != 0) return;
  int wild = 0;
  for (int i = 0; i < 256; ++i) {
    ushort u = emb_u16[i];
    int ex = (u >> 7) & 0xFF;
    if (u != 0 && (ex < 96 || ex > 159)) wild++;
  }
  flags[0] = (wild > 8) ? 1 : 0;
  int allz = 1, anynz = 0;
  for (int i = 0; i < 64; ++i) {
    if (x32[2 * i + 1] != 0) allz = 0;
    if (x32[2 * i] != 0) anynz = 1;
  }
  flags[1] = (allz && anynz) ? 2 : 1;
}

// zero watermark + chunk flags each launch (no hipMemsetAsync: graph-capture safe)
__global__ void init_sync(uint32_t* __restrict__ wm, uint32_t* __restrict__ cflag) {
  if (threadIdx.x < 8) wm[threadIdx.x] = 0;
  int n = 8 * NCHUNK;
  for (int i = threadIdx.x; i < n; i += 256) cflag[i] = 0;
}

// linear xh table (baseline path): embwb[v*512 + h]
template <int MODE>
__global__ void prep_embw(const void* __restrict__ embp, const void* __restrict__ wxhp,
                          const void* __restrict__ bhp, const int* __restrict__ flags,
                          float* __restrict__ embwb) {
  if (flags[0] != MODE) return;
  int gt = blockIdx.x * 256 + threadIdx.x;
  int v = gt >> 9, h = gt & 511;
  float s;
  if (MODE == 0) {
    const ushort* emb = (const ushort*)embp;
    const ushort* wxh = (const ushort*)wxhp;
    s = bf2f(((const ushort*)bhp)[h]);
#pragma unroll 8
    for (int e = 0; e < EMB; ++e) s += bf2f(emb[v * EMB + e]) * bf2f(wxh[e * HID + h]);
  } else {
    const float* emb = (const float*)embp;
    const float* wxh = (const float*)wxhp;
    s = ((const float*)bhp)[h];
#pragma unroll 8
    for (int e = 0; e < EMB; ++e) s += emb[v * EMB + e] * wxh[e * HID + h];
  }
  embwb[gt] = s;
}

// packed xh table (Path A): embwp[v*512 + (h&15)*32 + (h>>4)]
template <int MODE>
__global__ void prep_embw_pk(const void* __restrict__ embp, const void* __restrict__ wxhp,
                             const void* __restrict__ bhp, const int* __restrict__ flags,
                             float* __restrict__ embwp) {
  if (flags[0] != MODE) return;
  int gt = blockIdx.x * 256 + threadIdx.x;
  int v = gt >> 9, h = gt & 511;
  float s;
  if (MODE == 0) {
    const ushort* emb = (const ushort*)embp;
    const ushort* wxh = (const ushort*)wxhp;
    s = bf2f(((const ushort*)bhp)[h]);
#pragma unroll 8
    for (int e = 0; e < EMB; ++e) s += bf2f(emb[v * EMB + e]) * bf2f(wxh[e * HID + h]);
  } else {
    const float* emb = (const float*)embp;
    const float* wxh = (const float*)wxhp;
    s = ((const float*)bhp)[h];
#pragma unroll 8
    for (int e = 0; e < EMB; ++e) s += emb[v * EMB + e] * wxh[e * HID + h];
  }
  embwp[(size_t)v * HID + (h & 15) * 32 + (h >> 4)] = s;
}

// B-fragment prep for mfma_f32_16x16x32_bf16, layout [nt][kt][lane][8]
template <int MODE>
__global__ void prep_frag(const void* __restrict__ Wp, const int* __restrict__ flags,
                          ushort* __restrict__ out, int ncols) {
  if (flags[0] != MODE) return;
  int t = blockIdx.x * 256 + threadIdx.x;
  int lane = t & 63, kt = (t >> 6) & 15, nt = t >> 10;
  int n = nt * 16 + (lane & 15);
  int k0 = kt * 32 + (lane >> 4) * 8;
  ushort* o = out + (size_t)t * 8;
  if (MODE == 0) {
    const ushort* W = (const ushort*)Wp;
#pragma unroll
    for (int j = 0; j < 8; ++j) o[j] = W[(size_t)(k0 + j) * ncols + n];
  } else {
    const float* W = (const float*)Wp;
#pragma unroll
    for (int j = 0; j < 8; ++j) o[j] = f2bf(W[(size_t)(k0 + j) * ncols + n]);
  }
}

// ===================== PATH B: original proven kernel (3487 us) =====================
template <int MODE>
__global__ __launch_bounds__(512, 2) void rnn_split(
    const int* __restrict__ x, const void* __restrict__ hiddenp,
    const float* __restrict__ embwb, const ushort* __restrict__ wf,
    const ushort* __restrict__ fwf, const void* __restrict__ fcbp,
    const int* __restrict__ flags, uint64_t* __restrict__ gbuf, void* __restrict__ outp) {
  if (flags[0] != MODE) return;
  const int xstr = flags[1];
  __shared__ __align__(16) ushort hlds[2][32 * LDS_G + 8];
  __shared__ __align__(16) ushort plds[2][32 * LDS_G + 8];
  __shared__ float biasl[VOC];
  const int tid = threadIdx.x;
  const int wid = tid >> 6, lane = tid & 63;
  const int q = lane >> 4, l15 = lane & 15;
  const int rg = blockIdx.x & 7, s = blockIdx.x >> 3;
  const int rbase = rg * 16;
  uint64_t* pkt_me = gbuf + (size_t)blockIdx.x * 2 * PKT;
  const uint64_t* pkt_pt = gbuf + (size_t)(blockIdx.x ^ 8) * 2 * PKT;

  if (tid < VOC)
    biasl[tid] = (MODE == 0) ? bf2f(((const ushort*)fcbp)[tid]) : ((const float*)fcbp)[tid];

  const int nt0 = s * 16 + 2 * wid;
  const uint4* Wf4 = (const uint4*)wf;
  bf16x8 Bo[2][8], Bp[2][8];
#pragma unroll
  for (int j = 0; j < 2; ++j)
#pragma unroll
    for (int ktl = 0; ktl < 8; ++ktl) {
      Bo[j][ktl] = *(const bf16x8*)(Wf4 + ((size_t)(nt0 + j) * 16 + (s * 8 + ktl)) * 64 + lane);
      Bp[j][ktl] = *(const bf16x8*)(Wf4 + ((size_t)(nt0 + j) * 16 + ((1 - s) * 8 + ktl)) * 64 + lane);
    }

  {
    int g = tid >> 4, m = tid & 15;
    uint4 v;
    if (MODE == 0) {
      v = *(const uint4*)&((const ushort*)hiddenp)[(size_t)(rbase + m) * HID + s * 256 + g * 8];
    } else {
      const float* hf = (const float*)hiddenp;
      ushort tmp[8];
#pragma unroll
      for (int j = 0; j < 8; ++j) tmp[j] = f2bf(hf[(size_t)(rbase + m) * HID + s * 256 + g * 8 + j]);
      v = *(const uint4*)tmp;
    }
    *(uint4*)&hlds[0][g * LDS_G + m * 8] = v;
  }
  {
    ushort v8[8];
#pragma unroll
    for (int k = 0; k < 8; ++k) {
      int j = k >> 2, i = k & 3;
      size_t r = rbase + q * 4 + i;
      size_t c = s * 256 + (2 * wid + j) * 16 + l15;
      v8[k] = (MODE == 0) ? ((const ushort*)hiddenp)[r * HID + c]
                          : f2bf(((const float*)hiddenp)[r * HID + c]);
    }
    uint64_t* dst = pkt_me + PKT + (size_t)tid * 3;
    pstore(dst + 0, pack3(v8[0], v8[1], v8[2], 1));
    pstore(dst + 1, pack3(v8[3], v8[4], v8[5], 1));
    pstore(dst + 2, pack3(v8[6], v8[7], 0, 1));
  }
  __syncthreads();

  const uint4* Ff4 = (const uint4*)fwf;
  float* outf = (float*)outp;
  ushort* outb = (ushort*)outp;
  const bool lw = (wid >= 5);
  const int lt = s * 3 + (wid - 5);

#pragma unroll 1
  for (int t = 0; t < SEQL; ++t) {
    const int rslot = t & 1, wslot = (t + 1) & 1, pp = (t + 1) & 1;
    const uint32_t tag = (uint32_t)(t + 1);
    const uint64_t* psrc = pkt_pt + (size_t)pp * PKT + (size_t)tid * 3;
    uint64_t p0 = pload(psrc + 0);
    uint64_t p1 = pload(psrc + 1);
    uint64_t p2 = pload(psrc + 2);

    bf16x8 a[8];
#pragma unroll
    for (int ktl = 0; ktl < 8; ++ktl)
      a[ktl] = *(const bf16x8*)&hlds[rslot][(ktl * 4 + q) * LDS_G + l15 * 8];
    int xi[4];
#pragma unroll
    for (int rgi = 0; rgi < 4; ++rgi)
      xi[rgi] = x[(size_t)((rbase + q * 4 + rgi) * SEQL + t) * xstr];
    float ew[2][4];
#pragma unroll
    for (int j = 0; j < 2; ++j) {
      int n = (nt0 + j) * 16 + l15;
#pragma unroll
      for (int rgi = 0; rgi < 4; ++rgi) ew[j][rgi] = embwb[(size_t)xi[rgi] * HID + n];
    }
    f32x4 c0 = {0.f, 0.f, 0.f, 0.f}, c1 = {0.f, 0.f, 0.f, 0.f}, lc = {0.f, 0.f, 0.f, 0.f};
#pragma unroll
    for (int ktl = 0; ktl < 8; ++ktl) {
      c0 = __builtin_amdgcn_mfma_f32_16x16x32_bf16(a[ktl], Bo[0][ktl], c0, 0, 0, 0);
      c1 = __builtin_amdgcn_mfma_f32_16x16x32_bf16(a[ktl], Bo[1][ktl], c1, 0, 0, 0);
    }
    if (lw) {
#pragma unroll
      for (int ktl = 0; ktl < 8; ++ktl) {
        bf16x8 f = *(const bf16x8*)(Ff4 + ((size_t)lt * 16 + s * 8 + ktl) * 64 + lane);
        lc = __builtin_amdgcn_mfma_f32_16x16x32_bf16(a[ktl], f, lc, 0, 0, 0);
      }
    }

    while ((uint32_t)(p0 >> 48) != tag) { __builtin_amdgcn_s_sleep(1); p0 = pload(psrc + 0); }
    while ((uint32_t)(p1 >> 48) != tag) { __builtin_amdgcn_s_sleep(1); p1 = pload(psrc + 1); }
    while ((uint32_t)(p2 >> 48) != tag) { __builtin_amdgcn_s_sleep(1); p2 = pload(psrc + 2); }
    {
      ushort w8[8] = {(ushort)p0, (ushort)(p0 >> 16), (ushort)(p0 >> 32),
                      (ushort)p1, (ushort)(p1 >> 16), (ushort)(p1 >> 32),
                      (ushort)p2, (ushort)(p2 >> 16)};
#pragma unroll
      for (int k = 0; k < 8; ++k) {
        int j = k >> 2, i = k & 3;
        int c = (2 * wid + j) * 16 + l15;
        int r = q * 4 + i;
        plds[pp][(c >> 3) * LDS_G + r * 8 + (c & 7)] = w8[k];
      }
    }
    __syncthreads();

    bf16x8 ap[8];
#pragma unroll
    for (int ktl = 0; ktl < 8; ++ktl)
      ap[ktl] = *(const bf16x8*)&plds[pp][(ktl * 4 + q) * LDS_G + l15 * 8];
#pragma unroll
    for (int ktl = 0; ktl < 8; ++ktl) {
      c0 = __builtin_amdgcn_mfma_f32_16x16x32_bf16(ap[ktl], Bp[0][ktl], c0, 0, 0, 0);
      c1 = __builtin_amdgcn_mfma_f32_16x16x32_bf16(ap[ktl], Bp[1][ktl], c1, 0, 0, 0);
    }
    if (lw) {
#pragma unroll
      for (int ktl = 0; ktl < 8; ++ktl) {
        bf16x8 f = *(const bf16x8*)(Ff4 + ((size_t)lt * 16 + (1 - s) * 8 + ktl) * 64 + lane);
        lc = __builtin_amdgcn_mfma_f32_16x16x32_bf16(ap[ktl], f, lc, 0, 0, 0);
      }
      if (t > 0) {
        int n = lt * 16 + l15;
        float bv = biasl[n];
#pragma unroll
        for (int rgi = 0; rgi < 4; ++rgi) {
          size_t idx = ((size_t)(rbase + q * 4 + rgi) * SEQL + (t - 1)) * VOC + n;
          float val = lc[rgi] + bv;
          if (MODE == 0) outb[idx] = f2bf(val); else outf[idx] = val;
        }
      }
    }

    ushort hv[8];
#pragma unroll
    for (int rgi = 0; rgi < 4; ++rgi) hv[rgi]     = f2bf(fast_tanh(c0[rgi] + ew[0][rgi]));
#pragma unroll
    for (int rgi = 0; rgi < 4; ++rgi) hv[4 + rgi] = f2bf(fast_tanh(c1[rgi] + ew[1][rgi]));
    {
      uint64_t* dst = pkt_me + (size_t)(t & 1) * PKT + (size_t)tid * 3;
      uint32_t ntag = (uint32_t)(t + 2);
      pstore(dst + 0, pack3(hv[0], hv[1], hv[2], ntag));
      pstore(dst + 1, pack3(hv[3], hv[4], hv[5], ntag));
      pstore(dst + 2, pack3(hv[6], hv[7], 0, ntag));
    }
#pragma unroll
    for (int j = 0; j < 2; ++j) {
      int nl = (2 * wid + j) * 16 + l15;
      int base = (nl >> 3) * LDS_G + (nl & 7);
#pragma unroll
      for (int rgi = 0; rgi < 4; ++rgi) hlds[wslot][base + (q * 4 + rgi) * 8] = hv[j * 4 + rgi];
    }
    __syncthreads();
  }

  {
    const uint32_t tag = (uint32_t)(SEQL + 1);
    const uint64_t* psrc = pkt_pt + PKT + (size_t)tid * 3;
    uint64_t p0 = pload(psrc + 0);
    uint64_t p1 = pload(psrc + 1);
    uint64_t p2 = pload(psrc + 2);
    while ((uint32_t)(p0 >> 48) != tag) { __builtin_amdgcn_s_sleep(1); p0 = pload(psrc + 0); }
    while ((uint32_t)(p1 >> 48) != tag) { __builtin_amdgcn_s_sleep(1); p1 = pload(psrc + 1); }
    while ((uint32_t)(p2 >> 48) != tag) { __builtin_amdgcn_s_sleep(1); p2 = pload(psrc + 2); }
    ushort w8[8] = {(ushort)p0, (ushort)(p0 >> 16), (ushort)(p0 >> 32),
                    (ushort)p1, (ushort)(p1 >> 16), (ushort)(p1 >> 32),
                    (ushort)p2, (ushort)(p2 >> 16)};
#pragma unroll
    for (int k = 0; k < 8; ++k) {
      int j = k >> 2, i = k & 3;
      int c = (2 * wid + j) * 16 + l15;
      int r = q * 4 + i;
      plds[1][(c >> 3) * LDS_G + r * 8 + (c & 7)] = w8[k];
    }
  }
  __syncthreads();
  if (lw) {
    f32x4 lc = {0.f, 0.f, 0.f, 0.f};
#pragma unroll
    for (int ktl = 0; ktl < 8; ++ktl) {
      bf16x8 av = *(const bf16x8*)&hlds[0][(ktl * 4 + q) * LDS_G + l15 * 8];
      bf16x8 f = *(const bf16x8*)(Ff4 + ((size_t)lt * 16 + s * 8 + ktl) * 64 + lane);
      lc = __builtin_amdgcn_mfma_f32_16x16x32_bf16(av, f, lc, 0, 0, 0);
    }
#pragma unroll
    for (int ktl = 0; ktl < 8; ++ktl) {
      bf16x8 av = *(const bf16x8*)&plds[1][(ktl * 4 + q) * LDS_G + l15 * 8];
      bf16x8 f = *(const bf16x8*)(Ff4 + ((size_t)lt * 16 + (1 - s) * 8 + ktl) * 64 + lane);
      lc = __builtin_amdgcn_mfma_f32_16x16x32_bf16(av, f, lc, 0, 0, 0);
    }
    int n = lt * 16 + l15;
    float bv = biasl[n];
#pragma unroll
    for (int rgi = 0; rgi < 4; ++rgi) {
      size_t idx = ((size_t)(rbase + q * 4 + rgi) * SEQL + (SEQL - 1)) * VOC + n;
      float val = lc[rgi] + bv;
      if (MODE == 0) outb[idx] = f2bf(val); else outf[idx] = val;
    }
  }
  {
    int g = tid >> 4, m = tid & 15;
    if (MODE == 0) {
      *(uint4*)&outb[(size_t)B_SZ * SEQL * VOC + (size_t)(rbase + m) * HID + s * 256 + g * 8] =
          *(const uint4*)&hlds[0][g * LDS_G + m * 8];
    } else {
      float* fh = outf + (size_t)B_SZ * SEQL * VOC;
#pragma unroll
      for (int j = 0; j < 8; ++j)
        fh[(size_t)(rbase + m) * HID + s * 256 + g * 8 + j] = bf2f(hlds[0][g * LDS_G + m * 8 + j]);
    }
  }
}

// ===================== PATH A: decoupled producer/consumer =====================
#define REG_KT(nt) ((nt) < 5 ? 12 : 11)
#define RIDX(nt, kt) ((nt) < 5 ? (nt) * 12 + (kt) : 60 + ((nt) - 5) * 11 + (kt))
#define LIDX(nt, kt) ((nt) < 5 ? (nt) * 4 + ((kt) - 12) : 20 + ((nt) - 5) * 5 + ((kt) - 11))
#define NFRAG_LDS 35
#define NFRAG_REG 93

// blocks 0..7: producers — round-2 recurrence core (proven clean: 248 VGPR, no spill)
//   + 8 fire-and-forget SYSTEM-scope stores/step (drained one K-loop later)
//   + watermark every 32 steps.
// blocks 8..255: consumers — one 34-step chunk each, persistent fc_w registers,
//   single watermark wait per chunk. Ring depth R gated by cflag (off critical path).
// All cross-block traffic uses SYSTEM scope (the round-2-proven coherence path).
template <int MODE>
__global__ __launch_bounds__(256, 1) void rnn_pc2(
    const int* __restrict__ x, const void* __restrict__ hiddenp,
    const float* __restrict__ embwp, const ushort* __restrict__ wf,
    const ushort* __restrict__ fwf, const void* __restrict__ fcbp,
    const int* __restrict__ flags, uint64_t* __restrict__ hstream,
    uint32_t* __restrict__ wm, uint32_t* __restrict__ cflag, int R,
    void* __restrict__ outp) {
  if (flags[0] != MODE) return;
  const int xstr = flags[1];
  __shared__ __align__(16) ushort lds_w[140 * 512];
  __shared__ __align__(16) ushort lds_h[16 * 512];
  const int tid = threadIdx.x;
  const int wid = tid >> 6, lane = tid & 63;
  const int q = lane >> 4, l15 = lane & 15;
  const int hwb = wid * 2048 + q * 32 + (l15 >> 3) * 128 + (l15 & 7);
  const size_t BSLV = (size_t)B_SZ * SEQL * VOC;

  if (blockIdx.x < 8) {
    // ---------------- producer ----------------
    const int rg = blockIdx.x, rbase = rg * 16;
    const uint4* Wf4 = (const uint4*)wf;
    bf16x8 Wr[NFRAG_REG];
#pragma unroll
    for (int nt = 0; nt < 8; ++nt) {
#pragma unroll
      for (int kt = 0; kt < 16; ++kt) {
        const uint4* s4 = Wf4 + (((size_t)(8 * wid + nt) * 16 + kt) * 64 + lane);
        if (kt < REG_KT(nt)) {
          Wr[RIDX(nt, kt)] = *(const bf16x8*)s4;
        } else {
          *(uint4*)&lds_w[((size_t)wid * NFRAG_LDS + LIDX(nt, kt)) * 512 + lane * 8] = *s4;
        }
      }
    }
#pragma unroll
    for (int k = 0; k < 32; ++k) {
      int nt = k >> 2, i = k & 3;
      int r = rbase + q * 4 + i, c = (8 * wid + nt) * 16 + l15;
      ushort v = (MODE == 0) ? ((const ushort*)hiddenp)[(size_t)r * HID + c]
                             : f2bf(((const float*)hiddenp)[(size_t)r * HID + c]);
      lds_h[hwb + (nt >> 1) * 512 + (nt & 1) * 256 + i * 8] = v;
    }
    __syncthreads();

    int c = 0, tloc = 0, budget = 1 << 14;
    uint64_t* sbase = hstream + (size_t)rg * R * SLOT_U64;
#pragma unroll 1
    for (int t = 0; t < SEQL; ++t) {
      if (tloc == 0 && c) {
        if (c >= R) {  // slot reuse gate: chunk c-R must be consumed (expected instant)
          while (budget > 0 &&
                 __hip_atomic_load(cflag + rg * NCHUNK + (c - R), __ATOMIC_ACQUIRE,
                                   __HIP_MEMORY_SCOPE_SYSTEM) == 0u) {
            --budget;
            __builtin_amdgcn_s_sleep(8);
          }
        }
        sbase = hstream + ((size_t)rg * R + (size_t)(c % R)) * SLOT_U64;
      }
      int xi[4];
#pragma unroll
      for (int i = 0; i < 4; ++i)
        xi[i] = x[((size_t)(rbase + q * 4 + i) * SEQL + t) * xstr];
      f32x4 er[4][2];
#pragma unroll
      for (int i = 0; i < 4; ++i) {
        const f32x4* ef = (const f32x4*)(embwp + (size_t)xi[i] * HID + l15 * 32 + wid * 8);
        er[i][0] = ef[0];
        er[i][1] = ef[1];
      }
      f32x4 acc[8];
#pragma unroll
      for (int nt = 0; nt < 8; ++nt) acc[nt] = (f32x4){0.f, 0.f, 0.f, 0.f};

      bf16x8 ar0 = *(const bf16x8*)&lds_h[0 * 512 + lane * 8];
      bf16x8 ar1 = *(const bf16x8*)&lds_h[1 * 512 + lane * 8];
#pragma unroll
      for (int kt = 0; kt < 16; ++kt) {
        bf16x8 acur = (kt & 1) ? ar1 : ar0;
        if (kt + 2 < 16) {
          bf16x8 nx = *(const bf16x8*)&lds_h[(kt + 2) * 512 + lane * 8];
          if (kt & 1) ar1 = nx; else ar0 = nx;
        }
#pragma unroll
        for (int nt = 0; nt < 8; ++nt) {
          if (kt >= REG_KT(nt)) {
            bf16x8 b = *(const bf16x8*)
                &lds_w[((size_t)wid * NFRAG_LDS + LIDX(nt, kt)) * 512 + lane * 8];
            acc[nt] = __builtin_amdgcn_mfma_f32_16x16x32_bf16(acur, b, acc[nt], 0, 0, 0);
          } else {
            acc[nt] = __builtin_amdgcn_mfma_f32_16x16x32_bf16(acur, Wr[RIDX(nt, kt)],
                                                              acc[nt], 0, 0, 0);
          }
        }
      }
      ushort hv[32];
#pragma unroll
      for (int nt = 0; nt < 8; ++nt)
#pragma unroll
        for (int i = 0; i < 4; ++i)
          hv[nt * 4 + i] = f2bf(fast_tanh(acc[nt][i] + er[i][nt >> 2][nt & 3]));

      __syncthreads();  // reads of h_{t-1} done; drains h-stores of step t-1
      if (tid == 0 && t && (t & 31) == 0)
        __hip_atomic_store(wm + rg, (uint32_t)t, __ATOMIC_RELEASE,
                           __HIP_MEMORY_SCOPE_SYSTEM);
#pragma unroll
      for (int k = 0; k < 32; ++k) {
        int nt = k >> 2, i = k & 3;
        lds_h[hwb + (nt >> 1) * 512 + (nt & 1) * 256 + i * 8] = hv[k];
      }
      __syncthreads();  // h_t visible

      // fire-and-forget h_t publish (drains at NEXT step's first barrier)
      {
        uint64_t* dst = sbase + (size_t)tloc * TU64 + (size_t)tid * 8;
#pragma unroll
        for (int j = 0; j < 8; ++j) {
          uint64_t pv = (uint64_t)hv[4 * j] | ((uint64_t)hv[4 * j + 1] << 16) |
                        ((uint64_t)hv[4 * j + 2] << 32) | ((uint64_t)hv[4 * j + 3] << 48);
          pstore(dst + j, pv);
        }
      }
      if (++tloc == CHUNK) { tloc = 0; ++c; }
    }
    // final hidden state
    {
      int r = tid >> 4, fk = tid & 15;
      if (MODE == 0) {
        ushort vv[32];
#pragma unroll
        for (int cc = 0; cc < 32; ++cc)
          vv[cc] = lds_h[fk * 512 + (r + ((cc >> 3) & 3) * 16) * 8 + (cc & 7)];
        ushort* o = (ushort*)outp + BSLV + (size_t)(rbase + r) * HID + fk * 32;
#pragma unroll
        for (int m = 0; m < 4; ++m) *(uint4*)(o + m * 8) = *(const uint4*)&vv[m * 8];
      } else {
        float* o = (float*)outp + BSLV + (size_t)(rbase + r) * HID + fk * 32;
#pragma unroll
        for (int cc = 0; cc < 32; ++cc)
          o[cc] = bf2f(lds_h[fk * 512 + (r + ((cc >> 3) & 3) * 16) * 8 + (cc & 7)]);
      }
    }
    __syncthreads();  // drain all stores (incl. last chunk h-stores)
    if (tid == 0)
      __hip_atomic_store(wm + rg, (uint32_t)SEQL, __ATOMIC_RELEASE,
                         __HIP_MEMORY_SCOPE_SYSTEM);
  } else {
    // ---------------- consumer: one 34-step chunk of logits ----------------
    const int idx = (int)blockIdx.x - 8;
    const int rg = idx & 7, c = idx >> 3;
    const int rbase = rg * 16;
    const uint4* Ff4 = (const uint4*)fwf;
    const int base = (wid < 2) ? 2 * wid : wid + 2;  // waves own tiles {0,1},{2,3},{4},{5}
    const bool two = (wid < 2);
    bf16x8 Fc0[16], Fc1[16];
#pragma unroll
    for (int kt = 0; kt < 16; ++kt) {
      Fc0[kt] = *(const bf16x8*)(Ff4 + ((size_t)(base * 16 + kt) * 64 + lane));
      Fc1[kt] = two ? *(const bf16x8*)(Ff4 + ((size_t)((base + 1) * 16 + kt) * 64 + lane))
                    : Fc0[kt];
    }
    float b0 = (MODE == 0) ? bf2f(((const ushort*)fcbp)[base * 16 + l15])
                           : ((const float*)fcbp)[base * 16 + l15];
    float b1 = two ? ((MODE == 0) ? bf2f(((const ushort*)fcbp)[(base + 1) * 16 + l15])
                                  : ((const float*)fcbp)[(base + 1) * 16 + l15])
                   : 0.f;
    ushort* outb = (ushort*)outp;
    float* outf = (float*)outp;

    const int t0 = c * CHUNK;
    const int te = (t0 + CHUNK < SEQL) ? (t0 + CHUNK) : SEQL;
    int budget = 1 << 16;
    while (budget > 0 &&
           (int)__hip_atomic_load(wm + rg, __ATOMIC_ACQUIRE,
                                  __HIP_MEMORY_SCOPE_SYSTEM) < te) {
      --budget;
      __builtin_amdgcn_s_sleep(16);
    }
    const uint64_t* sb = hstream + ((size_t)rg * R + (size_t)(c % R)) * SLOT_U64;
#pragma unroll 1
    for (int t = t0; t < te; ++t) {
      const uint64_t* src = sb + (size_t)(t - t0) * TU64 + (size_t)tid * 8;
      uint64_t p[8];
#pragma unroll
      for (int j = 0; j < 8; ++j) p[j] = pload(src + j);
#pragma unroll
      for (int k = 0; k < 32; ++k) {
        int nt = k >> 2, i = k & 3;
        ushort v = (ushort)(p[k >> 2] >> (16 * (k & 3)));
        lds_h[hwb + (nt >> 1) * 512 + (nt & 1) * 256 + i * 8] = v;
      }
      __syncthreads();
      f32x4 c0 = {0.f, 0.f, 0.f, 0.f}, c1 = {0.f, 0.f, 0.f, 0.f};
#pragma unroll
      for (int kt = 0; kt < 16; ++kt) {
        bf16x8 a = *(const bf16x8*)&lds_h[kt * 512 + lane * 8];
        c0 = __builtin_amdgcn_mfma_f32_16x16x32_bf16(a, Fc0[kt], c0, 0, 0, 0);
        if (two) c1 = __builtin_amdgcn_mfma_f32_16x16x32_bf16(a, Fc1[kt], c1, 0, 0, 0);
      }
#pragma unroll
      for (int i = 0; i < 4; ++i) {
        size_t row = (size_t)(rbase + q * 4 + i) * SEQL + t;
        float v0 = c0[i] + b0;
        size_t i0 = row * VOC + base * 16 + l15;
        if (MODE == 0) outb[i0] = f2bf(v0); else outf[i0] = v0;
        if (two) {
          float v1 = c1[i] + b1;
          size_t i1 = row * VOC + (base + 1) * 16 + l15;
          if (MODE == 0) outb[i1] = f2bf(v1); else outf[i1] = v1;
        }
      }
      __syncthreads();
    }
    __syncthreads();  // drain logits stores, then free the ring slot
    if (tid == 0)
      __hip_atomic_store(cflag + rg * NCHUNK + c, 1u, __ATOMIC_RELEASE,
                         __HIP_MEMORY_SCOPE_SYSTEM);
  }
}

extern "C" void kernel_launch(void* const* d_in, const int* in_sizes, int n_in,
                              void* d_out, int out_size, void* d_ws, size_t ws_size,
                              hipStream_t stream) {
  const void* x      = d_in[0];
  const void* hidden = d_in[1];
  const void* emb    = d_in[2];
  const void* wxh    = d_in[3];
  const void* whh    = d_in[4];
  const void* bh     = d_in[5];
  const void* fcw    = d_in[6];
  const void* fcb    = d_in[7];

  char* ws = (char*)d_ws;
  int*      flags  = (int*)ws;                      // 256 B
  float*    embwb  = (float*)(ws + 256);            // 196608 B (linear xh table, Path B)
  ushort*   wfrag  = (ushort*)(ws + 196864);        // 524288 B (W_hh frags)
  ushort*   fwfrag = (ushort*)(ws + 721152);        // 98304 B  (fc_w frags)

  detect_kernel<<<1, 64, 0, stream>>>((const ushort*)emb, (const int*)x, flags);

  prep_frag<0><<<128, 256, 0, stream>>>(whh, flags, wfrag, HID);
  prep_frag<1><<<128, 256, 0, stream>>>(whh, flags, wfrag, HID);
  prep_frag<0><<<24, 256, 0, stream>>>(fcw, flags, fwfrag, VOC);
  prep_frag<1><<<24, 256, 0, stream>>>(fcw, flags, fwfrag, VOC);

  // Path A layout (overlaps Path B's gbuf region; only one path runs):
  const size_t emwp_off = 819456;                   // 196608 B packed xh table
  const size_t wm_off   = 1016064;                  // 256 B
  const size_t cf_off   = 1016320;                  // 1024 B
  const size_t hs_off   = 1017344;                  // R * 4456448 B h-stream ring
  const size_t slot_all = (size_t)8 * SLOT_U64 * 8; // 4456448

  long Rl = 0;
  if (ws_size >= hs_off + 3 * slot_all) Rl = (long)((ws_size - hs_off) / slot_all);
  int R = (int)(Rl > NCHUNK ? NCHUNK : Rl);

  if (R >= 3) {
    float* embwp = (float*)(ws + emwp_off);
    uint32_t* wm = (uint32_t*)(ws + wm_off);
    uint32_t* cflag = (uint32_t*)(ws + cf_off);
    uint64_t* hstream = (uint64_t*)(ws + hs_off);
    init_sync<<<1, 256, 0, stream>>>(wm, cflag);
    prep_embw_pk<0><<<192, 256, 0, stream>>>(emb, wxh, bh, flags, embwp);
    prep_embw_pk<1><<<192, 256, 0, stream>>>(emb, wxh, bh, flags, embwp);
    rnn_pc2<0><<<8 + 8 * NCHUNK, 256, 0, stream>>>((const int*)x, hidden, embwp, wfrag,
                                                   fwfrag, fcb, flags, hstream, wm, cflag,
                                                   R, d_out);
    rnn_pc2<1><<<8 + 8 * NCHUNK, 256, 0, stream>>>((const int*)x, hidden, embwp, wfrag,
                                                   fwfrag, fcb, flags, hstream, wm, cflag,
                                                   R, d_out);
  } else if (ws_size == 0 || ws_size >= 1212672) {
    // Path B: original proven kernel (3487 us)
    uint64_t* gbuf = (uint64_t*)(ws + 819456);      // 393216 B
    prep_embw<0><<<192, 256, 0, stream>>>(emb, wxh, bh, flags, embwb);
    prep_embw<1><<<192, 256, 0, stream>>>(emb, wxh, bh, flags, embwb);
    rnn_split<0><<<16, 512, 0, stream>>>((const int*)x, hidden, embwb, wfrag, fwfrag, fcb,
                                         flags, gbuf, d_out);
    rnn_split<1><<<16, 512, 0, stream>>>((const int*)x, hidden, embwb, wfrag, fwfrag, fcb,
                                         flags, gbuf, d_out);
  }
}

// Round 6
// 4370.592 us; speedup vs baseline: 3.3035x; 3.3035x over previous
//
#include <hip/hip_runtime.h>
#include <stdint.h>

#define B_SZ 128
#define SEQL 1024
#define EMB  64
#define HID  512
#define VOC  96
#define LDS_G 136
#define PKT  1536   // baseline kernel: 512 threads * 3 packets per parity

// Path-A stream geometry
#define CHUNK 34
#define NCHUNK 31
#define TU64 2048                        // u64 per (rg,t) = 16 KB
#define SLOT_U64 (CHUNK * TU64)          // 69632 u64 per (rg,chunk-slot)

typedef __attribute__((ext_vector_type(8))) short bf16x8;
typedef __attribute__((ext_vector_type(4))) float f32x4;

__device__ __forceinline__ float bf2f(ushort u) {
  union { uint32_t i; float f; } c; c.i = ((uint32_t)u) << 16; return c.f;
}
__device__ __forceinline__ ushort f2bf(float f) {
  union { float f; uint32_t i; } c; c.f = f;
  uint32_t u = c.i;
  return (ushort)((u + 0x7fffu + ((u >> 16) & 1u)) >> 16);
}
__device__ __forceinline__ float fast_tanh(float v) {
  float e = __expf(2.0f * v);
  return (e - 1.0f) * __builtin_amdgcn_rcpf(e + 1.0f);
}
__device__ __forceinline__ uint64_t pack3(ushort a, ushort b, ushort c, uint32_t tag) {
  return (uint64_t)a | ((uint64_t)b << 16) | ((uint64_t)c << 32) | ((uint64_t)tag << 48);
}
__device__ __forceinline__ uint64_t pload(const uint64_t* p) {
  return __hip_atomic_load((uint64_t*)p, __ATOMIC_RELAXED, __HIP_MEMORY_SCOPE_SYSTEM);
}
__device__ __forceinline__ void pstore(uint64_t* p, uint64_t v) {
  __hip_atomic_store(p, v, __ATOMIC_RELAXED, __HIP_MEMORY_SCOPE_SYSTEM);
}
__device__ __forceinline__ uint32_t rload32(const uint32_t* p) {
  return __hip_atomic_load((uint32_t*)p, __ATOMIC_RELAXED, __HIP_MEMORY_SCOPE_SYSTEM);
}
__device__ __forceinline__ void rstore32(uint32_t* p, uint32_t v) {
  __hip_atomic_store(p, v, __ATOMIC_RELAXED, __HIP_MEMORY_SCOPE_SYSTEM);
}

// flags[0]=dtype mode (0 bf16 / 1 f32); flags[1]=x stride (1 int32 / 2 int64)
__global__ void detect_kernel(const ushort* __restrict__ emb_u16,
                              const int* __restrict__ x32, int* __restrict__ flags) {
  if (blockIdx.x != 0 || threadIdx.x != 0) return;
  int wild = 0;
  for (int i = 0; i < 256; ++i) {
    ushort u = emb_u16[i];
    int ex = (u >> 7) & 0xFF;
    if (u != 0 && (ex < 96 || ex > 159)) wild++;
  }
  flags[0] = (wild > 8) ? 1 : 0;
  int allz = 1, anynz = 0;
  for (int i = 0; i < 64; ++i) {
    if (x32[2 * i + 1] != 0) allz = 0;
    if (x32[2 * i] != 0) anynz = 1;
  }
  flags[1] = (allz && anynz) ? 2 : 1;
}

// zero watermark + chunk flags each launch (no hipMemsetAsync: graph-capture safe)
__global__ void init_sync(uint32_t* __restrict__ wm, uint32_t* __restrict__ cflag) {
  if (threadIdx.x < 8) wm[threadIdx.x] = 0;
  int n = 8 * NCHUNK;
  for (int i = threadIdx.x; i < n; i += 256) cflag[i] = 0;
}

// linear xh table (baseline path): embwb[v*512 + h]
template <int MODE>
__global__ void prep_embw(const void* __restrict__ embp, const void* __restrict__ wxhp,
                          const void* __restrict__ bhp, const int* __restrict__ flags,
                          float* __restrict__ embwb) {
  if (flags[0] != MODE) return;
  int gt = blockIdx.x * 256 + threadIdx.x;
  int v = gt >> 9, h = gt & 511;
  float s;
  if (MODE == 0) {
    const ushort* emb = (const ushort*)embp;
    const ushort* wxh = (const ushort*)wxhp;
    s = bf2f(((const ushort*)bhp)[h]);
#pragma unroll 8
    for (int e = 0; e < EMB; ++e) s += bf2f(emb[v * EMB + e]) * bf2f(wxh[e * HID + h]);
  } else {
    const float* emb = (const float*)embp;
    const float* wxh = (const float*)wxhp;
    s = ((const float*)bhp)[h];
#pragma unroll 8
    for (int e = 0; e < EMB; ++e) s += emb[v * EMB + e] * wxh[e * HID + h];
  }
  embwb[gt] = s;
}

// packed xh table (Path A): embwp[v*512 + (h&15)*32 + (h>>4)]
template <int MODE>
__global__ void prep_embw_pk(const void* __restrict__ embp, const void* __restrict__ wxhp,
                             const void* __restrict__ bhp, const int* __restrict__ flags,
                             float* __restrict__ embwp) {
  if (flags[0] != MODE) return;
  int gt = blockIdx.x * 256 + threadIdx.x;
  int v = gt >> 9, h = gt & 511;
  float s;
  if (MODE == 0) {
    const ushort* emb = (const ushort*)embp;
    const ushort* wxh = (const ushort*)wxhp;
    s = bf2f(((const ushort*)bhp)[h]);
#pragma unroll 8
    for (int e = 0; e < EMB; ++e) s += bf2f(emb[v * EMB + e]) * bf2f(wxh[e * HID + h]);
  } else {
    const float* emb = (const float*)embp;
    const float* wxh = (const float*)wxhp;
    s = ((const float*)bhp)[h];
#pragma unroll 8
    for (int e = 0; e < EMB; ++e) s += emb[v * EMB + e] * wxh[e * HID + h];
  }
  embwp[(size_t)v * HID + (h & 15) * 32 + (h >> 4)] = s;
}

// B-fragment prep for mfma_f32_16x16x32_bf16, layout [nt][kt][lane][8]
template <int MODE>
__global__ void prep_frag(const void* __restrict__ Wp, const int* __restrict__ flags,
                          ushort* __restrict__ out, int ncols) {
  if (flags[0] != MODE) return;
  int t = blockIdx.x * 256 + threadIdx.x;
  int lane = t & 63, kt = (t >> 6) & 15, nt = t >> 10;
  int n = nt * 16 + (lane & 15);
  int k0 = kt * 32 + (lane >> 4) * 8;
  ushort* o = out + (size_t)t * 8;
  if (MODE == 0) {
    const ushort* W = (const ushort*)Wp;
#pragma unroll
    for (int j = 0; j < 8; ++j) o[j] = W[(size_t)(k0 + j) * ncols + n];
  } else {
    const float* W = (const float*)Wp;
#pragma unroll
    for (int j = 0; j < 8; ++j) o[j] = f2bf(W[(size_t)(k0 + j) * ncols + n]);
  }
}

// ===================== PATH B: original proven kernel (3487 us) =====================
template <int MODE>
__global__ __launch_bounds__(512, 2) void rnn_split(
    const int* __restrict__ x, const void* __restrict__ hiddenp,
    const float* __restrict__ embwb, const ushort* __restrict__ wf,
    const ushort* __restrict__ fwf, const void* __restrict__ fcbp,
    const int* __restrict__ flags, uint64_t* __restrict__ gbuf, void* __restrict__ outp) {
  if (flags[0] != MODE) return;
  const int xstr = flags[1];
  __shared__ __align__(16) ushort hlds[2][32 * LDS_G + 8];
  __shared__ __align__(16) ushort plds[2][32 * LDS_G + 8];
  __shared__ float biasl[VOC];
  const int tid = threadIdx.x;
  const int wid = tid >> 6, lane = tid & 63;
  const int q = lane >> 4, l15 = lane & 15;
  const int rg = blockIdx.x & 7, s = blockIdx.x >> 3;
  const int rbase = rg * 16;
  uint64_t* pkt_me = gbuf + (size_t)blockIdx.x * 2 * PKT;
  const uint64_t* pkt_pt = gbuf + (size_t)(blockIdx.x ^ 8) * 2 * PKT;

  if (tid < VOC)
    biasl[tid] = (MODE == 0) ? bf2f(((const ushort*)fcbp)[tid]) : ((const float*)fcbp)[tid];

  const int nt0 = s * 16 + 2 * wid;
  const uint4* Wf4 = (const uint4*)wf;
  bf16x8 Bo[2][8], Bp[2][8];
#pragma unroll
  for (int j = 0; j < 2; ++j)
#pragma unroll
    for (int ktl = 0; ktl < 8; ++ktl) {
      Bo[j][ktl] = *(const bf16x8*)(Wf4 + ((size_t)(nt0 + j) * 16 + (s * 8 + ktl)) * 64 + lane);
      Bp[j][ktl] = *(const bf16x8*)(Wf4 + ((size_t)(nt0 + j) * 16 + ((1 - s) * 8 + ktl)) * 64 + lane);
    }

  {
    int g = tid >> 4, m = tid & 15;
    uint4 v;
    if (MODE == 0) {
      v = *(const uint4*)&((const ushort*)hiddenp)[(size_t)(rbase + m) * HID + s * 256 + g * 8];
    } else {
      const float* hf = (const float*)hiddenp;
      ushort tmp[8];
#pragma unroll
      for (int j = 0; j < 8; ++j) tmp[j] = f2bf(hf[(size_t)(rbase + m) * HID + s * 256 + g * 8 + j]);
      v = *(const uint4*)tmp;
    }
    *(uint4*)&hlds[0][g * LDS_G + m * 8] = v;
  }
  {
    ushort v8[8];
#pragma unroll
    for (int k = 0; k < 8; ++k) {
      int j = k >> 2, i = k & 3;
      size_t r = rbase + q * 4 + i;
      size_t c = s * 256 + (2 * wid + j) * 16 + l15;
      v8[k] = (MODE == 0) ? ((const ushort*)hiddenp)[r * HID + c]
                          : f2bf(((const float*)hiddenp)[r * HID + c]);
    }
    uint64_t* dst = pkt_me + PKT + (size_t)tid * 3;
    pstore(dst + 0, pack3(v8[0], v8[1], v8[2], 1));
    pstore(dst + 1, pack3(v8[3], v8[4], v8[5], 1));
    pstore(dst + 2, pack3(v8[6], v8[7], 0, 1));
  }
  __syncthreads();

  const uint4* Ff4 = (const uint4*)fwf;
  float* outf = (float*)outp;
  ushort* outb = (ushort*)outp;
  const bool lw = (wid >= 5);
  const int lt = s * 3 + (wid - 5);

#pragma unroll 1
  for (int t = 0; t < SEQL; ++t) {
    const int rslot = t & 1, wslot = (t + 1) & 1, pp = (t + 1) & 1;
    const uint32_t tag = (uint32_t)(t + 1);
    const uint64_t* psrc = pkt_pt + (size_t)pp * PKT + (size_t)tid * 3;
    uint64_t p0 = pload(psrc + 0);
    uint64_t p1 = pload(psrc + 1);
    uint64_t p2 = pload(psrc + 2);

    bf16x8 a[8];
#pragma unroll
    for (int ktl = 0; ktl < 8; ++ktl)
      a[ktl] = *(const bf16x8*)&hlds[rslot][(ktl * 4 + q) * LDS_G + l15 * 8];
    int xi[4];
#pragma unroll
    for (int rgi = 0; rgi < 4; ++rgi)
      xi[rgi] = x[(size_t)((rbase + q * 4 + rgi) * SEQL + t) * xstr];
    float ew[2][4];
#pragma unroll
    for (int j = 0; j < 2; ++j) {
      int n = (nt0 + j) * 16 + l15;
#pragma unroll
      for (int rgi = 0; rgi < 4; ++rgi) ew[j][rgi] = embwb[(size_t)xi[rgi] * HID + n];
    }
    f32x4 c0 = {0.f, 0.f, 0.f, 0.f}, c1 = {0.f, 0.f, 0.f, 0.f}, lc = {0.f, 0.f, 0.f, 0.f};
#pragma unroll
    for (int ktl = 0; ktl < 8; ++ktl) {
      c0 = __builtin_amdgcn_mfma_f32_16x16x32_bf16(a[ktl], Bo[0][ktl], c0, 0, 0, 0);
      c1 = __builtin_amdgcn_mfma_f32_16x16x32_bf16(a[ktl], Bo[1][ktl], c1, 0, 0, 0);
    }
    if (lw) {
#pragma unroll
      for (int ktl = 0; ktl < 8; ++ktl) {
        bf16x8 f = *(const bf16x8*)(Ff4 + ((size_t)lt * 16 + s * 8 + ktl) * 64 + lane);
        lc = __builtin_amdgcn_mfma_f32_16x16x32_bf16(a[ktl], f, lc, 0, 0, 0);
      }
    }

    while ((uint32_t)(p0 >> 48) != tag) { __builtin_amdgcn_s_sleep(1); p0 = pload(psrc + 0); }
    while ((uint32_t)(p1 >> 48) != tag) { __builtin_amdgcn_s_sleep(1); p1 = pload(psrc + 1); }
    while ((uint32_t)(p2 >> 48) != tag) { __builtin_amdgcn_s_sleep(1); p2 = pload(psrc + 2); }
    {
      ushort w8[8] = {(ushort)p0, (ushort)(p0 >> 16), (ushort)(p0 >> 32),
                      (ushort)p1, (ushort)(p1 >> 16), (ushort)(p1 >> 32),
                      (ushort)p2, (ushort)(p2 >> 16)};
#pragma unroll
      for (int k = 0; k < 8; ++k) {
        int j = k >> 2, i = k & 3;
        int c = (2 * wid + j) * 16 + l15;
        int r = q * 4 + i;
        plds[pp][(c >> 3) * LDS_G + r * 8 + (c & 7)] = w8[k];
      }
    }
    __syncthreads();

    bf16x8 ap[8];
#pragma unroll
    for (int ktl = 0; ktl < 8; ++ktl)
      ap[ktl] = *(const bf16x8*)&plds[pp][(ktl * 4 + q) * LDS_G + l15 * 8];
#pragma unroll
    for (int ktl = 0; ktl < 8; ++ktl) {
      c0 = __builtin_amdgcn_mfma_f32_16x16x32_bf16(ap[ktl], Bp[0][ktl], c0, 0, 0, 0);
      c1 = __builtin_amdgcn_mfma_f32_16x16x32_bf16(ap[ktl], Bp[1][ktl], c1, 0, 0, 0);
    }
    if (lw) {
#pragma unroll
      for (int ktl = 0; ktl < 8; ++ktl) {
        bf16x8 f = *(const bf16x8*)(Ff4 + ((size_t)lt * 16 + (1 - s) * 8 + ktl) * 64 + lane);
        lc = __builtin_amdgcn_mfma_f32_16x16x32_bf16(ap[ktl], f, lc, 0, 0, 0);
      }
      if (t > 0) {
        int n = lt * 16 + l15;
        float bv = biasl[n];
#pragma unroll
        for (int rgi = 0; rgi < 4; ++rgi) {
          size_t idx = ((size_t)(rbase + q * 4 + rgi) * SEQL + (t - 1)) * VOC + n;
          float val = lc[rgi] + bv;
          if (MODE == 0) outb[idx] = f2bf(val); else outf[idx] = val;
        }
      }
    }

    ushort hv[8];
#pragma unroll
    for (int rgi = 0; rgi < 4; ++rgi) hv[rgi]     = f2bf(fast_tanh(c0[rgi] + ew[0][rgi]));
#pragma unroll
    for (int rgi = 0; rgi < 4; ++rgi) hv[4 + rgi] = f2bf(fast_tanh(c1[rgi] + ew[1][rgi]));
    {
      uint64_t* dst = pkt_me + (size_t)(t & 1) * PKT + (size_t)tid * 3;
      uint32_t ntag = (uint32_t)(t + 2);
      pstore(dst + 0, pack3(hv[0], hv[1], hv[2], ntag));
      pstore(dst + 1, pack3(hv[3], hv[4], hv[5], ntag));
      pstore(dst + 2, pack3(hv[6], hv[7], 0, ntag));
    }
#pragma unroll
    for (int j = 0; j < 2; ++j) {
      int nl = (2 * wid + j) * 16 + l15;
      int base = (nl >> 3) * LDS_G + (nl & 7);
#pragma unroll
      for (int rgi = 0; rgi < 4; ++rgi) hlds[wslot][base + (q * 4 + rgi) * 8] = hv[j * 4 + rgi];
    }
    __syncthreads();
  }

  {
    const uint32_t tag = (uint32_t)(SEQL + 1);
    const uint64_t* psrc = pkt_pt + PKT + (size_t)tid * 3;
    uint64_t p0 = pload(psrc + 0);
    uint64_t p1 = pload(psrc + 1);
    uint64_t p2 = pload(psrc + 2);
    while ((uint32_t)(p0 >> 48) != tag) { __builtin_amdgcn_s_sleep(1); p0 = pload(psrc + 0); }
    while ((uint32_t)(p1 >> 48) != tag) { __builtin_amdgcn_s_sleep(1); p1 = pload(psrc + 1); }
    while ((uint32_t)(p2 >> 48) != tag) { __builtin_amdgcn_s_sleep(1); p2 = pload(psrc + 2); }
    ushort w8[8] = {(ushort)p0, (ushort)(p0 >> 16), (ushort)(p0 >> 32),
                    (ushort)p1, (ushort)(p1 >> 16), (ushort)(p1 >> 32),
                    (ushort)p2, (ushort)(p2 >> 16)};
#pragma unroll
    for (int k = 0; k < 8; ++k) {
      int j = k >> 2, i = k & 3;
      int c = (2 * wid + j) * 16 + l15;
      int r = q * 4 + i;
      plds[1][(c >> 3) * LDS_G + r * 8 + (c & 7)] = w8[k];
    }
  }
  __syncthreads();
  if (lw) {
    f32x4 lc = {0.f, 0.f, 0.f, 0.f};
#pragma unroll
    for (int ktl = 0; ktl < 8; ++ktl) {
      bf16x8 av = *(const bf16x8*)&hlds[0][(ktl * 4 + q) * LDS_G + l15 * 8];
      bf16x8 f = *(const bf16x8*)(Ff4 + ((size_t)lt * 16 + s * 8 + ktl) * 64 + lane);
      lc = __builtin_amdgcn_mfma_f32_16x16x32_bf16(av, f, lc, 0, 0, 0);
    }
#pragma unroll
    for (int ktl = 0; ktl < 8; ++ktl) {
      bf16x8 av = *(const bf16x8*)&plds[1][(ktl * 4 + q) * LDS_G + l15 * 8];
      bf16x8 f = *(const bf16x8*)(Ff4 + ((size_t)lt * 16 + (1 - s) * 8 + ktl) * 64 + lane);
      lc = __builtin_amdgcn_mfma_f32_16x16x32_bf16(av, f, lc, 0, 0, 0);
    }
    int n = lt * 16 + l15;
    float bv = biasl[n];
#pragma unroll
    for (int rgi = 0; rgi < 4; ++rgi) {
      size_t idx = ((size_t)(rbase + q * 4 + rgi) * SEQL + (SEQL - 1)) * VOC + n;
      float val = lc[rgi] + bv;
      if (MODE == 0) outb[idx] = f2bf(val); else outf[idx] = val;
    }
  }
  {
    int g = tid >> 4, m = tid & 15;
    if (MODE == 0) {
      *(uint4*)&outb[(size_t)B_SZ * SEQL * VOC + (size_t)(rbase + m) * HID + s * 256 + g * 8] =
          *(const uint4*)&hlds[0][g * LDS_G + m * 8];
    } else {
      float* fh = outf + (size_t)B_SZ * SEQL * VOC;
#pragma unroll
      for (int j = 0; j < 8; ++j)
        fh[(size_t)(rbase + m) * HID + s * 256 + g * 8 + j] = bf2f(hlds[0][g * LDS_G + m * 8 + j]);
    }
  }
}

// ===================== PATH A: decoupled producer/consumer, cached-stream protocol ==
#define REG_KT(nt) ((nt) < 5 ? 12 : 11)
#define RIDX(nt, kt) ((nt) < 5 ? (nt) * 12 + (kt) : 60 + ((nt) - 5) * 11 + (kt))
#define LIDX(nt, kt) ((nt) < 5 ? (nt) * 4 + ((kt) - 12) : 20 + ((nt) - 5) * 5 + ((kt) - 11))
#define NFRAG_LDS 35
#define NFRAG_REG 93

// blocks 0..7: producers. h-publish = 4 plain coalesced uint4 stores/thread (L2
//   write-back, drained at next barrier ~L2 latency). Visibility: ONE
//   __threadfence_system (L2 writeback) + relaxed wm store per 34-step chunk.
// blocks 8..255: consumers. RELAXED system polls on wm (no L2 invalidate), one
//   __threadfence_system after the wait, then plain cached uint4 loads.
template <int MODE>
__global__ __launch_bounds__(256, 1) void rnn_pc3(
    const int* __restrict__ x, const void* __restrict__ hiddenp,
    const float* __restrict__ embwp, const ushort* __restrict__ wf,
    const ushort* __restrict__ fwf, const void* __restrict__ fcbp,
    const int* __restrict__ flags, uint4* __restrict__ hstream,
    uint32_t* __restrict__ wm, uint32_t* __restrict__ cflag, int R,
    void* __restrict__ outp) {
  if (flags[0] != MODE) return;
  const int xstr = flags[1];
  __shared__ __align__(16) ushort lds_w[140 * 512];
  __shared__ __align__(16) ushort lds_h[16 * 512];
  const int tid = threadIdx.x;
  const int wid = tid >> 6, lane = tid & 63;
  const int q = lane >> 4, l15 = lane & 15;
  const int hwb = wid * 2048 + q * 32 + (l15 >> 3) * 128 + (l15 & 7);
  const size_t BSLV = (size_t)B_SZ * SEQL * VOC;
  const size_t SLOT16 = SLOT_U64 / 2;  // slot size in 16B units

  if (blockIdx.x < 8) {
    // ---------------- producer ----------------
    const int rg = blockIdx.x, rbase = rg * 16;
    const uint4* Wf4 = (const uint4*)wf;
    bf16x8 Wr[NFRAG_REG];
#pragma unroll
    for (int nt = 0; nt < 8; ++nt) {
#pragma unroll
      for (int kt = 0; kt < 16; ++kt) {
        const uint4* s4 = Wf4 + (((size_t)(8 * wid + nt) * 16 + kt) * 64 + lane);
        if (kt < REG_KT(nt)) {
          Wr[RIDX(nt, kt)] = *(const bf16x8*)s4;
        } else {
          *(uint4*)&lds_w[((size_t)wid * NFRAG_LDS + LIDX(nt, kt)) * 512 + lane * 8] = *s4;
        }
      }
    }
#pragma unroll
    for (int k = 0; k < 32; ++k) {
      int nt = k >> 2, i = k & 3;
      int r = rbase + q * 4 + i, c = (8 * wid + nt) * 16 + l15;
      ushort v = (MODE == 0) ? ((const ushort*)hiddenp)[(size_t)r * HID + c]
                             : f2bf(((const float*)hiddenp)[(size_t)r * HID + c]);
      lds_h[hwb + (nt >> 1) * 512 + (nt & 1) * 256 + i * 8] = v;
    }
    __syncthreads();

    int c = 0, tloc = 0, budget = 1 << 14;
    bool need_wm = false;
    uint4* sbase = hstream + (size_t)rg * R * SLOT16;
#pragma unroll 1
    for (int t = 0; t < SEQL; ++t) {
      if (tloc == 0 && c) {
        need_wm = true;  // release wm = c*CHUNK after this step's first barrier
        if (c >= R) {    // slot reuse gate (relaxed flag; expected instant)
          while (budget > 0 && rload32(cflag + rg * NCHUNK + (c - R)) == 0u) {
            --budget;
            __builtin_amdgcn_s_sleep(8);
          }
        }
        sbase = hstream + ((size_t)rg * R + (size_t)(c % R)) * SLOT16;
      }
      int xi[4];
#pragma unroll
      for (int i = 0; i < 4; ++i)
        xi[i] = x[((size_t)(rbase + q * 4 + i) * SEQL + t) * xstr];
      f32x4 er[4][2];
#pragma unroll
      for (int i = 0; i < 4; ++i) {
        const f32x4* ef = (const f32x4*)(embwp + (size_t)xi[i] * HID + l15 * 32 + wid * 8);
        er[i][0] = ef[0];
        er[i][1] = ef[1];
      }
      f32x4 acc[8];
#pragma unroll
      for (int nt = 0; nt < 8; ++nt) acc[nt] = (f32x4){0.f, 0.f, 0.f, 0.f};

      bf16x8 ar0 = *(const bf16x8*)&lds_h[0 * 512 + lane * 8];
      bf16x8 ar1 = *(const bf16x8*)&lds_h[1 * 512 + lane * 8];
#pragma unroll
      for (int kt = 0; kt < 16; ++kt) {
        bf16x8 acur = (kt & 1) ? ar1 : ar0;
        if (kt + 2 < 16) {
          bf16x8 nx = *(const bf16x8*)&lds_h[(kt + 2) * 512 + lane * 8];
          if (kt & 1) ar1 = nx; else ar0 = nx;
        }
#pragma unroll
        for (int nt = 0; nt < 8; ++nt) {
          if (kt >= REG_KT(nt)) {
            bf16x8 b = *(const bf16x8*)
                &lds_w[((size_t)wid * NFRAG_LDS + LIDX(nt, kt)) * 512 + lane * 8];
            acc[nt] = __builtin_amdgcn_mfma_f32_16x16x32_bf16(acur, b, acc[nt], 0, 0, 0);
          } else {
            acc[nt] = __builtin_amdgcn_mfma_f32_16x16x32_bf16(acur, Wr[RIDX(nt, kt)],
                                                              acc[nt], 0, 0, 0);
          }
        }
      }
      ushort hv[32];
#pragma unroll
      for (int nt = 0; nt < 8; ++nt)
#pragma unroll
        for (int i = 0; i < 4; ++i)
          hv[nt * 4 + i] = f2bf(fast_tanh(acc[nt][i] + er[i][nt >> 2][nt & 3]));

      __syncthreads();  // reads of h_{t-1} done; drains publish stores of step t-1
      if (need_wm) {
        // prior chunk's stores all drained to L2 (barrier); flush L2 once, then mark
        if (tid == 0) {
          __threadfence_system();
          rstore32(wm + rg, (uint32_t)(c * CHUNK));
        }
        need_wm = false;
      }
#pragma unroll
      for (int k = 0; k < 32; ++k) {
        int nt = k >> 2, i = k & 3;
        lds_h[hwb + (nt >> 1) * 512 + (nt & 1) * 256 + i * 8] = hv[k];
      }
      __syncthreads();  // h_t visible

      // h_t publish: 4 plain coalesced uint4 stores (lane-adjacent 16B)
      {
        uint4* dst = sbase + (size_t)tloc * 1024 + tid;
#pragma unroll
        for (int j2 = 0; j2 < 4; ++j2) {
          uint4 pv;
          pv.x = (uint32_t)hv[8 * j2 + 0] | ((uint32_t)hv[8 * j2 + 1] << 16);
          pv.y = (uint32_t)hv[8 * j2 + 2] | ((uint32_t)hv[8 * j2 + 3] << 16);
          pv.z = (uint32_t)hv[8 * j2 + 4] | ((uint32_t)hv[8 * j2 + 5] << 16);
          pv.w = (uint32_t)hv[8 * j2 + 6] | ((uint32_t)hv[8 * j2 + 7] << 16);
          dst[j2 * 256] = pv;
        }
      }
      if (++tloc == CHUNK) { tloc = 0; ++c; }
    }
    // final hidden state
    {
      int r = tid >> 4, fk = tid & 15;
      if (MODE == 0) {
        ushort vv[32];
#pragma unroll
        for (int cc = 0; cc < 32; ++cc)
          vv[cc] = lds_h[fk * 512 + (r + ((cc >> 3) & 3) * 16) * 8 + (cc & 7)];
        ushort* o = (ushort*)outp + BSLV + (size_t)(rbase + r) * HID + fk * 32;
#pragma unroll
        for (int m = 0; m < 4; ++m) *(uint4*)(o + m * 8) = *(const uint4*)&vv[m * 8];
      } else {
        float* o = (float*)outp + BSLV + (size_t)(rbase + r) * HID + fk * 32;
#pragma unroll
        for (int cc = 0; cc < 32; ++cc)
          o[cc] = bf2f(lds_h[fk * 512 + (r + ((cc >> 3) & 3) * 16) * 8 + (cc & 7)]);
      }
    }
    __syncthreads();  // drain all stores (incl. last chunk h-stores)
    if (tid == 0) {
      __threadfence_system();
      rstore32(wm + rg, (uint32_t)SEQL);
    }
  } else {
    // ---------------- consumer: one 34-step chunk of logits ----------------
    const int idx = (int)blockIdx.x - 8;
    const int rg = idx & 7, c = idx >> 3;
    const int rbase = rg * 16;
    const uint4* Ff4 = (const uint4*)fwf;
    const int base = (wid < 2) ? 2 * wid : wid + 2;  // waves own tiles {0,1},{2,3},{4},{5}
    const bool two = (wid < 2);
    bf16x8 Fc0[16], Fc1[16];
#pragma unroll
    for (int kt = 0; kt < 16; ++kt) {
      Fc0[kt] = *(const bf16x8*)(Ff4 + ((size_t)(base * 16 + kt) * 64 + lane));
      Fc1[kt] = two ? *(const bf16x8*)(Ff4 + ((size_t)((base + 1) * 16 + kt) * 64 + lane))
                    : Fc0[kt];
    }
    float b0 = (MODE == 0) ? bf2f(((const ushort*)fcbp)[base * 16 + l15])
                           : ((const float*)fcbp)[base * 16 + l15];
    float b1 = two ? ((MODE == 0) ? bf2f(((const ushort*)fcbp)[(base + 1) * 16 + l15])
                                  : ((const float*)fcbp)[(base + 1) * 16 + l15])
                   : 0.f;
    ushort* outb = (ushort*)outp;
    float* outf = (float*)outp;

    const int t0 = c * CHUNK;
    const int te = (t0 + CHUNK < SEQL) ? (t0 + CHUNK) : SEQL;
    int budget = 1 << 15;
    // RELAXED poll (fresh value via system-scope load, no cache invalidate)
    while (budget > 0 && (int)rload32(wm + rg) < te) {
      --budget;
      __builtin_amdgcn_s_sleep(32);
    }
    __threadfence_system();  // one acquire-side flush/inv before reading the chunk
    const uint4* sb = hstream + ((size_t)rg * R + (size_t)(c % R)) * SLOT16;
#pragma unroll 1
    for (int t = t0; t < te; ++t) {
      const uint4* src = sb + (size_t)(t - t0) * 1024 + tid;
      uint4 e[4];
#pragma unroll
      for (int j2 = 0; j2 < 4; ++j2) e[j2] = src[j2 * 256];
#pragma unroll
      for (int k = 0; k < 32; ++k) {
        int nt = k >> 2, i = k & 3;
        uint32_t w = ((const uint32_t*)&e[k >> 3])[(k >> 1) & 3];
        ushort v = (ushort)(w >> (16 * (k & 1)));
        lds_h[hwb + (nt >> 1) * 512 + (nt & 1) * 256 + i * 8] = v;
      }
      __syncthreads();
      f32x4 c0 = {0.f, 0.f, 0.f, 0.f}, c1 = {0.f, 0.f, 0.f, 0.f};
#pragma unroll
      for (int kt = 0; kt < 16; ++kt) {
        bf16x8 a = *(const bf16x8*)&lds_h[kt * 512 + lane * 8];
        c0 = __builtin_amdgcn_mfma_f32_16x16x32_bf16(a, Fc0[kt], c0, 0, 0, 0);
        if (two) c1 = __builtin_amdgcn_mfma_f32_16x16x32_bf16(a, Fc1[kt], c1, 0, 0, 0);
      }
#pragma unroll
      for (int i = 0; i < 4; ++i) {
        size_t row = (size_t)(rbase + q * 4 + i) * SEQL + t;
        float v0 = c0[i] + b0;
        size_t i0 = row * VOC + base * 16 + l15;
        if (MODE == 0) outb[i0] = f2bf(v0); else outf[i0] = v0;
        if (two) {
          float v1 = c1[i] + b1;
          size_t i1 = row * VOC + (base + 1) * 16 + l15;
          if (MODE == 0) outb[i1] = f2bf(v1); else outf[i1] = v1;
        }
      }
      __syncthreads();
    }
    __syncthreads();  // all slot reads retired (barrier drained each thread's loads)
    if (tid == 0) rstore32(cflag + rg * NCHUNK + c, 1u);
  }
}

extern "C" void kernel_launch(void* const* d_in, const int* in_sizes, int n_in,
                              void* d_out, int out_size, void* d_ws, size_t ws_size,
                              hipStream_t stream) {
  const void* x      = d_in[0];
  const void* hidden = d_in[1];
  const void* emb    = d_in[2];
  const void* wxh    = d_in[3];
  const void* whh    = d_in[4];
  const void* bh     = d_in[5];
  const void* fcw    = d_in[6];
  const void* fcb    = d_in[7];

  char* ws = (char*)d_ws;
  int*      flags  = (int*)ws;                      // 256 B
  float*    embwb  = (float*)(ws + 256);            // 196608 B (linear xh table, Path B)
  ushort*   wfrag  = (ushort*)(ws + 196864);        // 524288 B (W_hh frags)
  ushort*   fwfrag = (ushort*)(ws + 721152);        // 98304 B  (fc_w frags)

  detect_kernel<<<1, 64, 0, stream>>>((const ushort*)emb, (const int*)x, flags);

  prep_frag<0><<<128, 256, 0, stream>>>(whh, flags, wfrag, HID);
  prep_frag<1><<<128, 256, 0, stream>>>(whh, flags, wfrag, HID);
  prep_frag<0><<<24, 256, 0, stream>>>(fcw, flags, fwfrag, VOC);
  prep_frag<1><<<24, 256, 0, stream>>>(fcw, flags, fwfrag, VOC);

  // Path A layout (overlaps Path B's gbuf region; only one path runs):
  const size_t emwp_off = 819456;                   // 196608 B packed xh table
  const size_t wm_off   = 1016064;                  // 256 B
  const size_t cf_off   = 1016320;                  // 1024 B
  const size_t hs_off   = 1017344;                  // R * 4456448 B h-stream ring
  const size_t slot_all = (size_t)8 * SLOT_U64 * 8; // 4456448

  long Rl = 0;
  if (ws_size >= hs_off + 3 * slot_all) Rl = (long)((ws_size - hs_off) / slot_all);
  int R = (int)(Rl > NCHUNK ? NCHUNK : Rl);

  if (R >= 3) {
    float* embwp = (float*)(ws + emwp_off);
    uint32_t* wm = (uint32_t*)(ws + wm_off);
    uint32_t* cflag = (uint32_t*)(ws + cf_off);
    uint4* hstream = (uint4*)(ws + hs_off);
    init_sync<<<1, 256, 0, stream>>>(wm, cflag);
    prep_embw_pk<0><<<192, 256, 0, stream>>>(emb, wxh, bh, flags, embwp);
    prep_embw_pk<1><<<192, 256, 0, stream>>>(emb, wxh, bh, flags, embwp);
    rnn_pc3<0><<<8 + 8 * NCHUNK, 256, 0, stream>>>((const int*)x, hidden, embwp, wfrag,
                                                   fwfrag, fcb, flags, hstream, wm, cflag,
                                                   R, d_out);
    rnn_pc3<1><<<8 + 8 * NCHUNK, 256, 0, stream>>>((const int*)x, hidden, embwp, wfrag,
                                                   fwfrag, fcb, flags, hstream, wm, cflag,
                                                   R, d_out);
  } else if (ws_size == 0 || ws_size >= 1212672) {
    // Path B: original proven kernel (3487 us)
    uint64_t* gbuf = (uint64_t*)(ws + 819456);      // 393216 B
    prep_embw<0><<<192, 256, 0, stream>>>(emb, wxh, bh, flags, embwb);
    prep_embw<1><<<192, 256, 0, stream>>>(emb, wxh, bh, flags, embwb);
    rnn_split<0><<<16, 512, 0, stream>>>((const int*)x, hidden, embwb, wfrag, fwfrag, fcb,
                                         flags, gbuf, d_out);
    rnn_split<1><<<16, 512, 0, stream>>>((const int*)x, hidden, embwb, wfrag, fwfrag, fcb,
                                         flags, gbuf, d_out);
  }
}

// Round 7
// 3479.380 us; speedup vs baseline: 4.1496x; 1.2561x over previous
//
#include <hip/hip_runtime.h>
#include <stdint.h>

#define B_SZ 128
#define SEQL 1024
#define EMB  64
#define HID  512
#define VOC  96
#define LDS_G 136
#define PKT  1536   // baseline kernel: 512 threads * 3 packets per parity

// Path-A stream geometry
#define CHUNK 34
#define NCHUNK 31
#define TU64 2048                        // u64 per (rg,t) = 16 KB
#define SLOT_U64 (CHUNK * TU64)          // 69632 u64 per (rg,chunk-slot)

typedef __attribute__((ext_vector_type(8))) short bf16x8;
typedef __attribute__((ext_vector_type(4))) float f32x4;

__device__ __forceinline__ float bf2f(ushort u) {
  union { uint32_t i; float f; } c; c.i = ((uint32_t)u) << 16; return c.f;
}
__device__ __forceinline__ ushort f2bf(float f) {
  union { float f; uint32_t i; } c; c.f = f;
  uint32_t u = c.i;
  return (ushort)((u + 0x7fffu + ((u >> 16) & 1u)) >> 16);
}
__device__ __forceinline__ float fast_tanh(float v) {
  float e = __expf(2.0f * v);
  return (e - 1.0f) * __builtin_amdgcn_rcpf(e + 1.0f);
}
__device__ __forceinline__ uint64_t pack3(ushort a, ushort b, ushort c, uint32_t tag) {
  return (uint64_t)a | ((uint64_t)b << 16) | ((uint64_t)c << 32) | ((uint64_t)tag << 48);
}
__device__ __forceinline__ uint64_t pload(const uint64_t* p) {
  return __hip_atomic_load((uint64_t*)p, __ATOMIC_RELAXED, __HIP_MEMORY_SCOPE_SYSTEM);
}
__device__ __forceinline__ void pstore(uint64_t* p, uint64_t v) {
  __hip_atomic_store(p, v, __ATOMIC_RELAXED, __HIP_MEMORY_SCOPE_SYSTEM);
}
__device__ __forceinline__ uint32_t rload32(const uint32_t* p) {
  return __hip_atomic_load((uint32_t*)p, __ATOMIC_RELAXED, __HIP_MEMORY_SCOPE_SYSTEM);
}
__device__ __forceinline__ void rstore32(uint32_t* p, uint32_t v) {
  __hip_atomic_store(p, v, __ATOMIC_RELAXED, __HIP_MEMORY_SCOPE_SYSTEM);
}

// flags[0]=dtype mode (0 bf16 / 1 f32); flags[1]=x stride (1 int32 / 2 int64)
__global__ void detect_kernel(const ushort* __restrict__ emb_u16,
                              const int* __restrict__ x32, int* __restrict__ flags) {
  if (blockIdx.x != 0 || threadIdx.x != 0) return;
  int wild = 0;
  for (int i = 0; i < 256; ++i) {
    ushort u = emb_u16[i];
    int ex = (u >> 7) & 0xFF;
    if (u != 0 && (ex < 96 || ex > 159)) wild++;
  }
  flags[0] = (wild > 8) ? 1 : 0;
  int allz = 1, anynz = 0;
  for (int i = 0; i < 64; ++i) {
    if (x32[2 * i + 1] != 0) allz = 0;
    if (x32[2 * i] != 0) anynz = 1;
  }
  flags[1] = (allz && anynz) ? 2 : 1;
}

// zero watermark + chunk flags each launch (no hipMemsetAsync: graph-capture safe)
__global__ void init_sync(uint32_t* __restrict__ wm, uint32_t* __restrict__ cflag) {
  if (threadIdx.x < 8) wm[threadIdx.x] = 0;
  int n = 8 * NCHUNK;
  for (int i = threadIdx.x; i < n; i += 256) cflag[i] = 0;
}

// linear xh table (baseline path): embwb[v*512 + h]
template <int MODE>
__global__ void prep_embw(const void* __restrict__ embp, const void* __restrict__ wxhp,
                          const void* __restrict__ bhp, const int* __restrict__ flags,
                          float* __restrict__ embwb) {
  if (flags[0] != MODE) return;
  int gt = blockIdx.x * 256 + threadIdx.x;
  int v = gt >> 9, h = gt & 511;
  float s;
  if (MODE == 0) {
    const ushort* emb = (const ushort*)embp;
    const ushort* wxh = (const ushort*)wxhp;
    s = bf2f(((const ushort*)bhp)[h]);
#pragma unroll 8
    for (int e = 0; e < EMB; ++e) s += bf2f(emb[v * EMB + e]) * bf2f(wxh[e * HID + h]);
  } else {
    const float* emb = (const float*)embp;
    const float* wxh = (const float*)wxhp;
    s = ((const float*)bhp)[h];
#pragma unroll 8
    for (int e = 0; e < EMB; ++e) s += emb[v * EMB + e] * wxh[e * HID + h];
  }
  embwb[gt] = s;
}

// packed xh table (Path A): embwp[v*512 + (h&15)*32 + (h>>4)]
template <int MODE>
__global__ void prep_embw_pk(const void* __restrict__ embp, const void* __restrict__ wxhp,
                             const void* __restrict__ bhp, const int* __restrict__ flags,
                             float* __restrict__ embwp) {
  if (flags[0] != MODE) return;
  int gt = blockIdx.x * 256 + threadIdx.x;
  int v = gt >> 9, h = gt & 511;
  float s;
  if (MODE == 0) {
    const ushort* emb = (const ushort*)embp;
    const ushort* wxh = (const ushort*)wxhp;
    s = bf2f(((const ushort*)bhp)[h]);
#pragma unroll 8
    for (int e = 0; e < EMB; ++e) s += bf2f(emb[v * EMB + e]) * bf2f(wxh[e * HID + h]);
  } else {
    const float* emb = (const float*)embp;
    const float* wxh = (const float*)wxhp;
    s = ((const float*)bhp)[h];
#pragma unroll 8
    for (int e = 0; e < EMB; ++e) s += emb[v * EMB + e] * wxh[e * HID + h];
  }
  embwp[(size_t)v * HID + (h & 15) * 32 + (h >> 4)] = s;
}

// B-fragment prep for mfma_f32_16x16x32_bf16, layout [nt][kt][lane][8]
template <int MODE>
__global__ void prep_frag(const void* __restrict__ Wp, const int* __restrict__ flags,
                          ushort* __restrict__ out, int ncols) {
  if (flags[0] != MODE) return;
  int t = blockIdx.x * 256 + threadIdx.x;
  int lane = t & 63, kt = (t >> 6) & 15, nt = t >> 10;
  int n = nt * 16 + (lane & 15);
  int k0 = kt * 32 + (lane >> 4) * 8;
  ushort* o = out + (size_t)t * 8;
  if (MODE == 0) {
    const ushort* W = (const ushort*)Wp;
#pragma unroll
    for (int j = 0; j < 8; ++j) o[j] = W[(size_t)(k0 + j) * ncols + n];
  } else {
    const float* W = (const float*)Wp;
#pragma unroll
    for (int j = 0; j < 8; ++j) o[j] = f2bf(W[(size_t)(k0 + j) * ncols + n]);
  }
}

// ===================== PATH B: original proven kernel (3487 us) =====================
template <int MODE>
__global__ __launch_bounds__(512, 2) void rnn_split(
    const int* __restrict__ x, const void* __restrict__ hiddenp,
    const float* __restrict__ embwb, const ushort* __restrict__ wf,
    const ushort* __restrict__ fwf, const void* __restrict__ fcbp,
    const int* __restrict__ flags, uint64_t* __restrict__ gbuf, void* __restrict__ outp) {
  if (flags[0] != MODE) return;
  const int xstr = flags[1];
  __shared__ __align__(16) ushort hlds[2][32 * LDS_G + 8];
  __shared__ __align__(16) ushort plds[2][32 * LDS_G + 8];
  __shared__ float biasl[VOC];
  const int tid = threadIdx.x;
  const int wid = tid >> 6, lane = tid & 63;
  const int q = lane >> 4, l15 = lane & 15;
  const int rg = blockIdx.x & 7, s = blockIdx.x >> 3;
  const int rbase = rg * 16;
  uint64_t* pkt_me = gbuf + (size_t)blockIdx.x * 2 * PKT;
  const uint64_t* pkt_pt = gbuf + (size_t)(blockIdx.x ^ 8) * 2 * PKT;

  if (tid < VOC)
    biasl[tid] = (MODE == 0) ? bf2f(((const ushort*)fcbp)[tid]) : ((const float*)fcbp)[tid];

  const int nt0 = s * 16 + 2 * wid;
  const uint4* Wf4 = (const uint4*)wf;
  bf16x8 Bo[2][8], Bp[2][8];
#pragma unroll
  for (int j = 0; j < 2; ++j)
#pragma unroll
    for (int ktl = 0; ktl < 8; ++ktl) {
      Bo[j][ktl] = *(const bf16x8*)(Wf4 + ((size_t)(nt0 + j) * 16 + (s * 8 + ktl)) * 64 + lane);
      Bp[j][ktl] = *(const bf16x8*)(Wf4 + ((size_t)(nt0 + j) * 16 + ((1 - s) * 8 + ktl)) * 64 + lane);
    }

  {
    int g = tid >> 4, m = tid & 15;
    uint4 v;
    if (MODE == 0) {
      v = *(const uint4*)&((const ushort*)hiddenp)[(size_t)(rbase + m) * HID + s * 256 + g * 8];
    } else {
      const float* hf = (const float*)hiddenp;
      ushort tmp[8];
#pragma unroll
      for (int j = 0; j < 8; ++j) tmp[j] = f2bf(hf[(size_t)(rbase + m) * HID + s * 256 + g * 8 + j]);
      v = *(const uint4*)tmp;
    }
    *(uint4*)&hlds[0][g * LDS_G + m * 8] = v;
  }
  {
    ushort v8[8];
#pragma unroll
    for (int k = 0; k < 8; ++k) {
      int j = k >> 2, i = k & 3;
      size_t r = rbase + q * 4 + i;
      size_t c = s * 256 + (2 * wid + j) * 16 + l15;
      v8[k] = (MODE == 0) ? ((const ushort*)hiddenp)[r * HID + c]
                          : f2bf(((const float*)hiddenp)[r * HID + c]);
    }
    uint64_t* dst = pkt_me + PKT + (size_t)tid * 3;
    pstore(dst + 0, pack3(v8[0], v8[1], v8[2], 1));
    pstore(dst + 1, pack3(v8[3], v8[4], v8[5], 1));
    pstore(dst + 2, pack3(v8[6], v8[7], 0, 1));
  }
  __syncthreads();

  const uint4* Ff4 = (const uint4*)fwf;
  float* outf = (float*)outp;
  ushort* outb = (ushort*)outp;
  const bool lw = (wid >= 5);
  const int lt = s * 3 + (wid - 5);

#pragma unroll 1
  for (int t = 0; t < SEQL; ++t) {
    const int rslot = t & 1, wslot = (t + 1) & 1, pp = (t + 1) & 1;
    const uint32_t tag = (uint32_t)(t + 1);
    const uint64_t* psrc = pkt_pt + (size_t)pp * PKT + (size_t)tid * 3;
    uint64_t p0 = pload(psrc + 0);
    uint64_t p1 = pload(psrc + 1);
    uint64_t p2 = pload(psrc + 2);

    bf16x8 a[8];
#pragma unroll
    for (int ktl = 0; ktl < 8; ++ktl)
      a[ktl] = *(const bf16x8*)&hlds[rslot][(ktl * 4 + q) * LDS_G + l15 * 8];
    int xi[4];
#pragma unroll
    for (int rgi = 0; rgi < 4; ++rgi)
      xi[rgi] = x[(size_t)((rbase + q * 4 + rgi) * SEQL + t) * xstr];
    float ew[2][4];
#pragma unroll
    for (int j = 0; j < 2; ++j) {
      int n = (nt0 + j) * 16 + l15;
#pragma unroll
      for (int rgi = 0; rgi < 4; ++rgi) ew[j][rgi] = embwb[(size_t)xi[rgi] * HID + n];
    }
    f32x4 c0 = {0.f, 0.f, 0.f, 0.f}, c1 = {0.f, 0.f, 0.f, 0.f}, lc = {0.f, 0.f, 0.f, 0.f};
#pragma unroll
    for (int ktl = 0; ktl < 8; ++ktl) {
      c0 = __builtin_amdgcn_mfma_f32_16x16x32_bf16(a[ktl], Bo[0][ktl], c0, 0, 0, 0);
      c1 = __builtin_amdgcn_mfma_f32_16x16x32_bf16(a[ktl], Bo[1][ktl], c1, 0, 0, 0);
    }
    if (lw) {
#pragma unroll
      for (int ktl = 0; ktl < 8; ++ktl) {
        bf16x8 f = *(const bf16x8*)(Ff4 + ((size_t)lt * 16 + s * 8 + ktl) * 64 + lane);
        lc = __builtin_amdgcn_mfma_f32_16x16x32_bf16(a[ktl], f, lc, 0, 0, 0);
      }
    }

    while ((uint32_t)(p0 >> 48) != tag) { __builtin_amdgcn_s_sleep(1); p0 = pload(psrc + 0); }
    while ((uint32_t)(p1 >> 48) != tag) { __builtin_amdgcn_s_sleep(1); p1 = pload(psrc + 1); }
    while ((uint32_t)(p2 >> 48) != tag) { __builtin_amdgcn_s_sleep(1); p2 = pload(psrc + 2); }
    {
      ushort w8[8] = {(ushort)p0, (ushort)(p0 >> 16), (ushort)(p0 >> 32),
                      (ushort)p1, (ushort)(p1 >> 16), (ushort)(p1 >> 32),
                      (ushort)p2, (ushort)(p2 >> 16)};
#pragma unroll
      for (int k = 0; k < 8; ++k) {
        int j = k >> 2, i = k & 3;
        int c = (2 * wid + j) * 16 + l15;
        int r = q * 4 + i;
        plds[pp][(c >> 3) * LDS_G + r * 8 + (c & 7)] = w8[k];
      }
    }
    __syncthreads();

    bf16x8 ap[8];
#pragma unroll
    for (int ktl = 0; ktl < 8; ++ktl)
      ap[ktl] = *(const bf16x8*)&plds[pp][(ktl * 4 + q) * LDS_G + l15 * 8];
#pragma unroll
    for (int ktl = 0; ktl < 8; ++ktl) {
      c0 = __builtin_amdgcn_mfma_f32_16x16x32_bf16(ap[ktl], Bp[0][ktl], c0, 0, 0, 0);
      c1 = __builtin_amdgcn_mfma_f32_16x16x32_bf16(ap[ktl], Bp[1][ktl], c1, 0, 0, 0);
    }
    if (lw) {
#pragma unroll
      for (int ktl = 0; ktl < 8; ++ktl) {
        bf16x8 f = *(const bf16x8*)(Ff4 + ((size_t)lt * 16 + (1 - s) * 8 + ktl) * 64 + lane);
        lc = __builtin_amdgcn_mfma_f32_16x16x32_bf16(ap[ktl], f, lc, 0, 0, 0);
      }
      if (t > 0) {
        int n = lt * 16 + l15;
        float bv = biasl[n];
#pragma unroll
        for (int rgi = 0; rgi < 4; ++rgi) {
          size_t idx = ((size_t)(rbase + q * 4 + rgi) * SEQL + (t - 1)) * VOC + n;
          float val = lc[rgi] + bv;
          if (MODE == 0) outb[idx] = f2bf(val); else outf[idx] = val;
        }
      }
    }

    ushort hv[8];
#pragma unroll
    for (int rgi = 0; rgi < 4; ++rgi) hv[rgi]     = f2bf(fast_tanh(c0[rgi] + ew[0][rgi]));
#pragma unroll
    for (int rgi = 0; rgi < 4; ++rgi) hv[4 + rgi] = f2bf(fast_tanh(c1[rgi] + ew[1][rgi]));
    {
      uint64_t* dst = pkt_me + (size_t)(t & 1) * PKT + (size_t)tid * 3;
      uint32_t ntag = (uint32_t)(t + 2);
      pstore(dst + 0, pack3(hv[0], hv[1], hv[2], ntag));
      pstore(dst + 1, pack3(hv[3], hv[4], hv[5], ntag));
      pstore(dst + 2, pack3(hv[6], hv[7], 0, ntag));
    }
#pragma unroll
    for (int j = 0; j < 2; ++j) {
      int nl = (2 * wid + j) * 16 + l15;
      int base = (nl >> 3) * LDS_G + (nl & 7);
#pragma unroll
      for (int rgi = 0; rgi < 4; ++rgi) hlds[wslot][base + (q * 4 + rgi) * 8] = hv[j * 4 + rgi];
    }
    __syncthreads();
  }

  {
    const uint32_t tag = (uint32_t)(SEQL + 1);
    const uint64_t* psrc = pkt_pt + PKT + (size_t)tid * 3;
    uint64_t p0 = pload(psrc + 0);
    uint64_t p1 = pload(psrc + 1);
    uint64_t p2 = pload(psrc + 2);
    while ((uint32_t)(p0 >> 48) != tag) { __builtin_amdgcn_s_sleep(1); p0 = pload(psrc + 0); }
    while ((uint32_t)(p1 >> 48) != tag) { __builtin_amdgcn_s_sleep(1); p1 = pload(psrc + 1); }
    while ((uint32_t)(p2 >> 48) != tag) { __builtin_amdgcn_s_sleep(1); p2 = pload(psrc + 2); }
    ushort w8[8] = {(ushort)p0, (ushort)(p0 >> 16), (ushort)(p0 >> 32),
                    (ushort)p1, (ushort)(p1 >> 16), (ushort)(p1 >> 32),
                    (ushort)p2, (ushort)(p2 >> 16)};
#pragma unroll
    for (int k = 0; k < 8; ++k) {
      int j = k >> 2, i = k & 3;
      int c = (2 * wid + j) * 16 + l15;
      int r = q * 4 + i;
      plds[1][(c >> 3) * LDS_G + r * 8 + (c & 7)] = w8[k];
    }
  }
  __syncthreads();
  if (lw) {
    f32x4 lc = {0.f, 0.f, 0.f, 0.f};
#pragma unroll
    for (int ktl = 0; ktl < 8; ++ktl) {
      bf16x8 av = *(const bf16x8*)&hlds[0][(ktl * 4 + q) * LDS_G + l15 * 8];
      bf16x8 f = *(const bf16x8*)(Ff4 + ((size_t)lt * 16 + s * 8 + ktl) * 64 + lane);
      lc = __builtin_amdgcn_mfma_f32_16x16x32_bf16(av, f, lc, 0, 0, 0);
    }
#pragma unroll
    for (int ktl = 0; ktl < 8; ++ktl) {
      bf16x8 av = *(const bf16x8*)&plds[1][(ktl * 4 + q) * LDS_G + l15 * 8];
      bf16x8 f = *(const bf16x8*)(Ff4 + ((size_t)lt * 16 + (1 - s) * 8 + ktl) * 64 + lane);
      lc = __builtin_amdgcn_mfma_f32_16x16x32_bf16(av, f, lc, 0, 0, 0);
    }
    int n = lt * 16 + l15;
    float bv = biasl[n];
#pragma unroll
    for (int rgi = 0; rgi < 4; ++rgi) {
      size_t idx = ((size_t)(rbase + q * 4 + rgi) * SEQL + (SEQL - 1)) * VOC + n;
      float val = lc[rgi] + bv;
      if (MODE == 0) outb[idx] = f2bf(val); else outf[idx] = val;
    }
  }
  {
    int g = tid >> 4, m = tid & 15;
    if (MODE == 0) {
      *(uint4*)&outb[(size_t)B_SZ * SEQL * VOC + (size_t)(rbase + m) * HID + s * 256 + g * 8] =
          *(const uint4*)&hlds[0][g * LDS_G + m * 8];
    } else {
      float* fh = outf + (size_t)B_SZ * SEQL * VOC;
#pragma unroll
      for (int j = 0; j < 8; ++j)
        fh[(size_t)(rbase + m) * HID + s * 256 + g * 8 + j] = bf2f(hlds[0][g * LDS_G + m * 8 + j]);
    }
  }
}

// ===================== PATH A: 8-wave producer / chunk consumers ====================
// W split per wave (4 nt-tiles x 16 kt = 64 frags): kt<14 in regs (56 frags = 224),
// kt 14,15 in LDS (8 frags/wave, 64 KB total).
#define RKT 14

template <int MODE>
__global__ __launch_bounds__(512, 2) void rnn_pc4(
    const int* __restrict__ x, const void* __restrict__ hiddenp,
    const float* __restrict__ embwp, const ushort* __restrict__ wf,
    const ushort* __restrict__ fwf, const void* __restrict__ fcbp,
    const int* __restrict__ flags, uint4* __restrict__ hstream,
    uint32_t* __restrict__ wm, uint32_t* __restrict__ cflag, int R,
    void* __restrict__ outp) {
  if (flags[0] != MODE) return;
  const int xstr = flags[1];
  __shared__ __align__(16) ushort lds_w[64 * 512];   // 64 KB producer W (kt 14,15)
  __shared__ __align__(16) ushort lds_h[2][16 * 512]; // 2 x 16 KB h double-buffer
  const int tid = threadIdx.x;
  const int wid = tid >> 6, lane = tid & 63;
  const int q = lane >> 4, l15 = lane & 15;
  const size_t BSLV = (size_t)B_SZ * SEQL * VOC;
  const size_t SLOT16 = SLOT_U64 / 2;  // slot size in 16B units

  if (blockIdx.x < 8) {
    // ---------------- producer: 8 waves, wave owns n-tiles 4*wid..4*wid+3 ----------
    const int rg = blockIdx.x, rbase = rg * 16;
    // canonical layout addr(r,c) = (c>>5)*512 + (((c>>3)&3)*16 + r)*8 + (c&7); for
    // this wave's writes: hwb8 + (j>>1)*512 + (j&1)*256 + i*8
    const int hwb8 = wid * 1024 + q * 32 + (l15 >> 3) * 128 + (l15 & 7);
    const uint4* Wf4 = (const uint4*)wf;
    bf16x8 Wr[4 * RKT];
#pragma unroll
    for (int j = 0; j < 4; ++j) {
      int g = 4 * wid + j;
#pragma unroll
      for (int kt = 0; kt < 16; ++kt) {
        const uint4* s4 = Wf4 + (((size_t)g * 16 + kt) * 64 + lane);
        if (kt < RKT) {
          Wr[j * RKT + kt] = *(const bf16x8*)s4;
        } else {
          *(uint4*)&lds_w[((size_t)(wid * 4 + j) * 2 + (kt - RKT)) * 512 + lane * 8] = *s4;
        }
      }
    }
    // stage h_{-1} into lds_h[0]
#pragma unroll
    for (int k = 0; k < 16; ++k) {
      int j = k >> 2, i = k & 3;
      int r = rbase + q * 4 + i, c = (4 * wid + j) * 16 + l15;
      ushort v = (MODE == 0) ? ((const ushort*)hiddenp)[(size_t)r * HID + c]
                             : f2bf(((const float*)hiddenp)[(size_t)r * HID + c]);
      lds_h[0][hwb8 + (j >> 1) * 512 + (j & 1) * 256 + i * 8] = v;
    }
    __syncthreads();

    const int base16 = (wid >> 1) * 64 + q * 16 + l15;  // stream pos (old 4-wave geom)
    const int jq = 2 * (wid & 1);                        // this wave's two quarters
    int c = 0, tloc = 0, budget = 1 << 14;
    uint4* sbase = hstream + (size_t)rg * R * SLOT16;
    ushort hv[16];
    bool have_pub = false;
#pragma unroll 1
    for (int t = 0; t < SEQL; ++t) {
      if (tloc == 0 && c) {
        if (c >= R) {  // slot reuse gate (relaxed; expected instant)
          while (budget > 0 && rload32(cflag + rg * NCHUNK + (c - R)) == 0u) {
            --budget;
            __builtin_amdgcn_s_sleep(8);
          }
        }
        sbase = hstream + ((size_t)rg * R + (size_t)(c % R)) * SLOT16;
      }
      const ushort* hb = lds_h[t & 1];
      ushort* hw = lds_h[(t + 1) & 1];
      int xi[4];
#pragma unroll
      for (int i = 0; i < 4; ++i)
        xi[i] = x[((size_t)(rbase + q * 4 + i) * SEQL + t) * xstr];
      f32x4 er[4];
#pragma unroll
      for (int i = 0; i < 4; ++i)
        er[i] = *(const f32x4*)(embwp + (size_t)xi[i] * HID + l15 * 32 + 4 * wid);
      f32x4 acc[4];
#pragma unroll
      for (int j = 0; j < 4; ++j) acc[j] = (f32x4){0.f, 0.f, 0.f, 0.f};

      bf16x8 ar0 = *(const bf16x8*)&hb[0 * 512 + lane * 8];
      bf16x8 ar1 = *(const bf16x8*)&hb[1 * 512 + lane * 8];
#pragma unroll
      for (int kt = 0; kt < 16; ++kt) {
        bf16x8 acur = (kt & 1) ? ar1 : ar0;
        if (kt + 2 < 16) {
          bf16x8 nx = *(const bf16x8*)&hb[(kt + 2) * 512 + lane * 8];
          if (kt & 1) ar1 = nx; else ar0 = nx;
        }
#pragma unroll
        for (int j = 0; j < 4; ++j) {
          if (kt >= RKT) {
            bf16x8 b = *(const bf16x8*)
                &lds_w[((size_t)(wid * 4 + j) * 2 + (kt - RKT)) * 512 + lane * 8];
            acc[j] = __builtin_amdgcn_mfma_f32_16x16x32_bf16(acur, b, acc[j], 0, 0, 0);
          } else {
            acc[j] = __builtin_amdgcn_mfma_f32_16x16x32_bf16(acur, Wr[j * RKT + kt],
                                                             acc[j], 0, 0, 0);
          }
        }
      }
      // h_t = tanh(acc + xh)
#pragma unroll
      for (int j = 0; j < 4; ++j)
#pragma unroll
        for (int i = 0; i < 4; ++i)
          hv[j * 4 + i] = f2bf(fast_tanh(acc[j][i] + er[i][j]));
      // write h_t to the other buffer (no barrier needed before: disjoint buffer)
#pragma unroll
      for (int k = 0; k < 16; ++k) {
        int j = k >> 2, i = k & 3;
        hw[hwb8 + (j >> 1) * 512 + (j & 1) * 256 + i * 8] = hv[k];
      }
      __syncthreads();  // h_t ready; drains publish stores of step t-1 (vmcnt 0)
      if (tid == 0 && tloc == 0 && c) {
        __threadfence_system();               // chunk c-1 drained to L2 -> flush once
        rstore32(wm + rg, (uint32_t)t);       // t == c*CHUNK
      }
      // publish h_t (fire-and-forget; drained at next step's barrier)
      {
        uint4* dst = sbase + (size_t)tloc * 1024 + base16;
#pragma unroll
        for (int jh = 0; jh < 2; ++jh) {
          uint4 pv;
          pv.x = (uint32_t)hv[8 * jh + 0] | ((uint32_t)hv[8 * jh + 1] << 16);
          pv.y = (uint32_t)hv[8 * jh + 2] | ((uint32_t)hv[8 * jh + 3] << 16);
          pv.z = (uint32_t)hv[8 * jh + 4] | ((uint32_t)hv[8 * jh + 5] << 16);
          pv.w = (uint32_t)hv[8 * jh + 6] | ((uint32_t)hv[8 * jh + 7] << 16);
          dst[(size_t)(jq + jh) * 256] = pv;
        }
        have_pub = true;
      }
      (void)have_pub;
      if (++tloc == CHUNK) { tloc = 0; ++c; }
    }
    // final hidden state (h_1023 is in lds_h[0]); first 256 threads, canonical layout
    if (tid < 256) {
      int r = tid >> 4, fk = tid & 15;
      if (MODE == 0) {
        ushort vv[32];
#pragma unroll
        for (int cc = 0; cc < 32; ++cc)
          vv[cc] = lds_h[0][fk * 512 + (r + ((cc >> 3) & 3) * 16) * 8 + (cc & 7)];
        ushort* o = (ushort*)outp + BSLV + (size_t)(rbase + r) * HID + fk * 32;
#pragma unroll
        for (int m = 0; m < 4; ++m) *(uint4*)(o + m * 8) = *(const uint4*)&vv[m * 8];
      } else {
        float* o = (float*)outp + BSLV + (size_t)(rbase + r) * HID + fk * 32;
#pragma unroll
        for (int cc = 0; cc < 32; ++cc)
          o[cc] = bf2f(lds_h[0][fk * 512 + (r + ((cc >> 3) & 3) * 16) * 8 + (cc & 7)]);
      }
    }
    __syncthreads();  // drain all stores (incl. last chunk publishes)
    if (tid == 0) {
      __threadfence_system();
      rstore32(wm + rg, (uint32_t)SEQL);
    }
  } else {
    // ---------------- consumer: one 34-step chunk of logits -----------------------
    const int idx = (int)blockIdx.x - 8;
    const int rg = idx & 7, c = idx >> 3;
    const int rbase = rg * 16;
    const uint4* Ff4 = (const uint4*)fwf;
    const bool act = (wid < 6);  // waves 0..5 own one vocab tile each
    bf16x8 Fc[16];
#pragma unroll
    for (int kt = 0; kt < 16; ++kt)
      Fc[kt] = act ? *(const bf16x8*)(Ff4 + ((size_t)(wid * 16 + kt) * 64 + lane))
                   : (bf16x8){0, 0, 0, 0, 0, 0, 0, 0};
    float b0 = act ? ((MODE == 0) ? bf2f(((const ushort*)fcbp)[wid * 16 + l15])
                                  : ((const float*)fcbp)[wid * 16 + l15])
                   : 0.f;
    ushort* outb = (ushort*)outp;
    float* outf = (float*)outp;
    // unpack geometry (old 256-thread form), used by tid<256 only
    const int hwb = (tid >> 6) * 2048 + q * 32 + (l15 >> 3) * 128 + (l15 & 7);

    const int t0 = c * CHUNK;
    const int te = (t0 + CHUNK < SEQL) ? (t0 + CHUNK) : SEQL;
    int budget = 1 << 15;
    while (budget > 0 && (int)rload32(wm + rg) < te) {
      --budget;
      __builtin_amdgcn_s_sleep(32);
    }
    __threadfence_system();  // one acquire-side inv before reading the chunk
    const uint4* sb = hstream + ((size_t)rg * R + (size_t)(c % R)) * SLOT16;
#pragma unroll 1
    for (int t = t0; t < te; ++t) {
      if (tid < 256) {
        const uint4* src = sb + (size_t)(t - t0) * 1024 + tid;
        uint4 e[4];
#pragma unroll
        for (int j2 = 0; j2 < 4; ++j2) e[j2] = src[j2 * 256];
#pragma unroll
        for (int k = 0; k < 32; ++k) {
          int nt = k >> 2, i = k & 3;
          uint32_t w = ((const uint32_t*)&e[k >> 3])[(k >> 1) & 3];
          ushort v = (ushort)(w >> (16 * (k & 1)));
          lds_h[0][hwb + (nt >> 1) * 512 + (nt & 1) * 256 + i * 8] = v;
        }
      }
      __syncthreads();
      if (act) {
        f32x4 c0 = {0.f, 0.f, 0.f, 0.f};
#pragma unroll
        for (int kt = 0; kt < 16; ++kt) {
          bf16x8 a = *(const bf16x8*)&lds_h[0][kt * 512 + lane * 8];
          c0 = __builtin_amdgcn_mfma_f32_16x16x32_bf16(a, Fc[kt], c0, 0, 0, 0);
        }
#pragma unroll
        for (int i = 0; i < 4; ++i) {
          size_t row = (size_t)(rbase + q * 4 + i) * SEQL + t;
          float v0 = c0[i] + b0;
          size_t i0 = row * VOC + wid * 16 + l15;
          if (MODE == 0) outb[i0] = f2bf(v0); else outf[i0] = v0;
        }
      }
      __syncthreads();
    }
    __syncthreads();
    if (tid == 0) rstore32(cflag + rg * NCHUNK + c, 1u);
  }
}

extern "C" void kernel_launch(void* const* d_in, const int* in_sizes, int n_in,
                              void* d_out, int out_size, void* d_ws, size_t ws_size,
                              hipStream_t stream) {
  const void* x      = d_in[0];
  const void* hidden = d_in[1];
  const void* emb    = d_in[2];
  const void* wxh    = d_in[3];
  const void* whh    = d_in[4];
  const void* bh     = d_in[5];
  const void* fcw    = d_in[6];
  const void* fcb    = d_in[7];

  char* ws = (char*)d_ws;
  int*      flags  = (int*)ws;                      // 256 B
  float*    embwb  = (float*)(ws + 256);            // 196608 B (linear xh table, Path B)
  ushort*   wfrag  = (ushort*)(ws + 196864);        // 524288 B (W_hh frags)
  ushort*   fwfrag = (ushort*)(ws + 721152);        // 98304 B  (fc_w frags)

  detect_kernel<<<1, 64, 0, stream>>>((const ushort*)emb, (const int*)x, flags);

  prep_frag<0><<<128, 256, 0, stream>>>(whh, flags, wfrag, HID);
  prep_frag<1><<<128, 256, 0, stream>>>(whh, flags, wfrag, HID);
  prep_frag<0><<<24, 256, 0, stream>>>(fcw, flags, fwfrag, VOC);
  prep_frag<1><<<24, 256, 0, stream>>>(fcw, flags, fwfrag, VOC);

  // Path A layout (overlaps Path B's gbuf region; only one path runs):
  const size_t emwp_off = 819456;                   // 196608 B packed xh table
  const size_t wm_off   = 1016064;                  // 256 B
  const size_t cf_off   = 1016320;                  // 1024 B
  const size_t hs_off   = 1017344;                  // R * 4456448 B h-stream ring
  const size_t slot_all = (size_t)8 * SLOT_U64 * 8; // 4456448

  long Rl = 0;
  if (ws_size >= hs_off + 3 * slot_all) Rl = (long)((ws_size - hs_off) / slot_all);
  int R = (int)(Rl > NCHUNK ? NCHUNK : Rl);

  if (R >= 3) {
    float* embwp = (float*)(ws + emwp_off);
    uint32_t* wm = (uint32_t*)(ws + wm_off);
    uint32_t* cflag = (uint32_t*)(ws + cf_off);
    uint4* hstream = (uint4*)(ws + hs_off);
    init_sync<<<1, 256, 0, stream>>>(wm, cflag);
    prep_embw_pk<0><<<192, 256, 0, stream>>>(emb, wxh, bh, flags, embwp);
    prep_embw_pk<1><<<192, 256, 0, stream>>>(emb, wxh, bh, flags, embwp);
    rnn_pc4<0><<<8 + 8 * NCHUNK, 512, 0, stream>>>((const int*)x, hidden, embwp, wfrag,
                                                   fwfrag, fcb, flags, hstream, wm, cflag,
                                                   R, d_out);
    rnn_pc4<1><<<8 + 8 * NCHUNK, 512, 0, stream>>>((const int*)x, hidden, embwp, wfrag,
                                                   fwfrag, fcb, flags, hstream, wm, cflag,
                                                   R, d_out);
  } else if (ws_size == 0 || ws_size >= 1212672) {
    // Path B: original proven kernel (3487 us)
    uint64_t* gbuf = (uint64_t*)(ws + 819456);      // 393216 B
    prep_embw<0><<<192, 256, 0, stream>>>(emb, wxh, bh, flags, embwb);
    prep_embw<1><<<192, 256, 0, stream>>>(emb, wxh, bh, flags, embwb);
    rnn_split<0><<<16, 512, 0, stream>>>((const int*)x, hidden, embwb, wfrag, fwfrag, fcb,
                                         flags, gbuf, d_out);
    rnn_split<1><<<16, 512, 0, stream>>>((const int*)x, hidden, embwb, wfrag, fwfrag, fcb,
                                         flags, gbuf, d_out);
  }
}

// Round 8
// 2590.772 us; speedup vs baseline: 5.5729x; 1.3430x over previous
//
#include <hip/hip_runtime.h>
#include <stdint.h>

#define B_SZ 128
#define SEQL 1024
#define EMB  64
#define HID  512
#define VOC  96
#define LDS_G 136
#define PKT  1536   // baseline kernel: 512 threads * 3 packets per parity

// Path-A stream geometry
#define CHUNK 34
#define NCHUNK 31
#define TU64 2048                        // u64 per (rg,t) = 16 KB
#define SLOT_U64 (CHUNK * TU64)          // 69632 u64 per (rg,chunk-slot)

typedef __attribute__((ext_vector_type(8))) short bf16x8;
typedef __attribute__((ext_vector_type(4))) float f32x4;

__device__ __forceinline__ float bf2f(ushort u) {
  union { uint32_t i; float f; } c; c.i = ((uint32_t)u) << 16; return c.f;
}
__device__ __forceinline__ ushort f2bf(float f) {
  union { float f; uint32_t i; } c; c.f = f;
  uint32_t u = c.i;
  return (ushort)((u + 0x7fffu + ((u >> 16) & 1u)) >> 16);
}
__device__ __forceinline__ float fast_tanh(float v) {
  float e = __expf(2.0f * v);
  return (e - 1.0f) * __builtin_amdgcn_rcpf(e + 1.0f);
}
__device__ __forceinline__ uint64_t pack3(ushort a, ushort b, ushort c, uint32_t tag) {
  return (uint64_t)a | ((uint64_t)b << 16) | ((uint64_t)c << 32) | ((uint64_t)tag << 48);
}
__device__ __forceinline__ uint64_t pload(const uint64_t* p) {
  return __hip_atomic_load((uint64_t*)p, __ATOMIC_RELAXED, __HIP_MEMORY_SCOPE_SYSTEM);
}
__device__ __forceinline__ void pstore(uint64_t* p, uint64_t v) {
  __hip_atomic_store(p, v, __ATOMIC_RELAXED, __HIP_MEMORY_SCOPE_SYSTEM);
}
__device__ __forceinline__ uint32_t rload32(const uint32_t* p) {
  return __hip_atomic_load((uint32_t*)p, __ATOMIC_RELAXED, __HIP_MEMORY_SCOPE_SYSTEM);
}
__device__ __forceinline__ void rstore32(uint32_t* p, uint32_t v) {
  __hip_atomic_store(p, v, __ATOMIC_RELAXED, __HIP_MEMORY_SCOPE_SYSTEM);
}

// flags[0]=dtype mode (0 bf16 / 1 f32); flags[1]=x stride (1 int32 / 2 int64)
__global__ void detect_kernel(const ushort* __restrict__ emb_u16,
                              const int* __restrict__ x32, int* __restrict__ flags) {
  if (blockIdx.x != 0 || threadIdx.x != 0) return;
  int wild = 0;
  for (int i = 0; i < 256; ++i) {
    ushort u = emb_u16[i];
    int ex = (u >> 7) & 0xFF;
    if (u != 0 && (ex < 96 || ex > 159)) wild++;
  }
  flags[0] = (wild > 8) ? 1 : 0;
  int allz = 1, anynz = 0;
  for (int i = 0; i < 64; ++i) {
    if (x32[2 * i + 1] != 0) allz = 0;
    if (x32[2 * i] != 0) anynz = 1;
  }
  flags[1] = (allz && anynz) ? 2 : 1;
}

// zero watermark + chunk flags each launch (no hipMemsetAsync: graph-capture safe)
__global__ void init_sync(uint32_t* __restrict__ wm, uint32_t* __restrict__ cflag) {
  if (threadIdx.x < 8) wm[threadIdx.x] = 0;
  int n = 8 * NCHUNK;
  for (int i = threadIdx.x; i < n; i += 256) cflag[i] = 0;
}

// linear xh table (baseline path): embwb[v*512 + h]
template <int MODE>
__global__ void prep_embw(const void* __restrict__ embp, const void* __restrict__ wxhp,
                          const void* __restrict__ bhp, const int* __restrict__ flags,
                          float* __restrict__ embwb) {
  if (flags[0] != MODE) return;
  int gt = blockIdx.x * 256 + threadIdx.x;
  int v = gt >> 9, h = gt & 511;
  float s;
  if (MODE == 0) {
    const ushort* emb = (const ushort*)embp;
    const ushort* wxh = (const ushort*)wxhp;
    s = bf2f(((const ushort*)bhp)[h]);
#pragma unroll 8
    for (int e = 0; e < EMB; ++e) s += bf2f(emb[v * EMB + e]) * bf2f(wxh[e * HID + h]);
  } else {
    const float* emb = (const float*)embp;
    const float* wxh = (const float*)wxhp;
    s = ((const float*)bhp)[h];
#pragma unroll 8
    for (int e = 0; e < EMB; ++e) s += emb[v * EMB + e] * wxh[e * HID + h];
  }
  embwb[gt] = s;
}

// packed xh table (Path A): embwp[v*512 + (h&15)*32 + (h>>4)]
template <int MODE>
__global__ void prep_embw_pk(const void* __restrict__ embp, const void* __restrict__ wxhp,
                             const void* __restrict__ bhp, const int* __restrict__ flags,
                             float* __restrict__ embwp) {
  if (flags[0] != MODE) return;
  int gt = blockIdx.x * 256 + threadIdx.x;
  int v = gt >> 9, h = gt & 511;
  float s;
  if (MODE == 0) {
    const ushort* emb = (const ushort*)embp;
    const ushort* wxh = (const ushort*)wxhp;
    s = bf2f(((const ushort*)bhp)[h]);
#pragma unroll 8
    for (int e = 0; e < EMB; ++e) s += bf2f(emb[v * EMB + e]) * bf2f(wxh[e * HID + h]);
  } else {
    const float* emb = (const float*)embp;
    const float* wxh = (const float*)wxhp;
    s = ((const float*)bhp)[h];
#pragma unroll 8
    for (int e = 0; e < EMB; ++e) s += emb[v * EMB + e] * wxh[e * HID + h];
  }
  embwp[(size_t)v * HID + (h & 15) * 32 + (h >> 4)] = s;
}

// B-fragment prep for mfma_f32_16x16x32_bf16, layout [nt][kt][lane][8]
template <int MODE>
__global__ void prep_frag(const void* __restrict__ Wp, const int* __restrict__ flags,
                          ushort* __restrict__ out, int ncols) {
  if (flags[0] != MODE) return;
  int t = blockIdx.x * 256 + threadIdx.x;
  int lane = t & 63, kt = (t >> 6) & 15, nt = t >> 10;
  int n = nt * 16 + (lane & 15);
  int k0 = kt * 32 + (lane >> 4) * 8;
  ushort* o = out + (size_t)t * 8;
  if (MODE == 0) {
    const ushort* W = (const ushort*)Wp;
#pragma unroll
    for (int j = 0; j < 8; ++j) o[j] = W[(size_t)(k0 + j) * ncols + n];
  } else {
    const float* W = (const float*)Wp;
#pragma unroll
    for (int j = 0; j < 8; ++j) o[j] = f2bf(W[(size_t)(k0 + j) * ncols + n]);
  }
}

// ===================== PATH B: original proven kernel (3487 us) =====================
template <int MODE>
__global__ __launch_bounds__(512, 2) void rnn_split(
    const int* __restrict__ x, const void* __restrict__ hiddenp,
    const float* __restrict__ embwb, const ushort* __restrict__ wf,
    const ushort* __restrict__ fwf, const void* __restrict__ fcbp,
    const int* __restrict__ flags, uint64_t* __restrict__ gbuf, void* __restrict__ outp) {
  if (flags[0] != MODE) return;
  const int xstr = flags[1];
  __shared__ __align__(16) ushort hlds[2][32 * LDS_G + 8];
  __shared__ __align__(16) ushort plds[2][32 * LDS_G + 8];
  __shared__ float biasl[VOC];
  const int tid = threadIdx.x;
  const int wid = tid >> 6, lane = tid & 63;
  const int q = lane >> 4, l15 = lane & 15;
  const int rg = blockIdx.x & 7, s = blockIdx.x >> 3;
  const int rbase = rg * 16;
  uint64_t* pkt_me = gbuf + (size_t)blockIdx.x * 2 * PKT;
  const uint64_t* pkt_pt = gbuf + (size_t)(blockIdx.x ^ 8) * 2 * PKT;

  if (tid < VOC)
    biasl[tid] = (MODE == 0) ? bf2f(((const ushort*)fcbp)[tid]) : ((const float*)fcbp)[tid];

  const int nt0 = s * 16 + 2 * wid;
  const uint4* Wf4 = (const uint4*)wf;
  bf16x8 Bo[2][8], Bp[2][8];
#pragma unroll
  for (int j = 0; j < 2; ++j)
#pragma unroll
    for (int ktl = 0; ktl < 8; ++ktl) {
      Bo[j][ktl] = *(const bf16x8*)(Wf4 + ((size_t)(nt0 + j) * 16 + (s * 8 + ktl)) * 64 + lane);
      Bp[j][ktl] = *(const bf16x8*)(Wf4 + ((size_t)(nt0 + j) * 16 + ((1 - s) * 8 + ktl)) * 64 + lane);
    }

  {
    int g = tid >> 4, m = tid & 15;
    uint4 v;
    if (MODE == 0) {
      v = *(const uint4*)&((const ushort*)hiddenp)[(size_t)(rbase + m) * HID + s * 256 + g * 8];
    } else {
      const float* hf = (const float*)hiddenp;
      ushort tmp[8];
#pragma unroll
      for (int j = 0; j < 8; ++j) tmp[j] = f2bf(hf[(size_t)(rbase + m) * HID + s * 256 + g * 8 + j]);
      v = *(const uint4*)tmp;
    }
    *(uint4*)&hlds[0][g * LDS_G + m * 8] = v;
  }
  {
    ushort v8[8];
#pragma unroll
    for (int k = 0; k < 8; ++k) {
      int j = k >> 2, i = k & 3;
      size_t r = rbase + q * 4 + i;
      size_t c = s * 256 + (2 * wid + j) * 16 + l15;
      v8[k] = (MODE == 0) ? ((const ushort*)hiddenp)[r * HID + c]
                          : f2bf(((const float*)hiddenp)[r * HID + c]);
    }
    uint64_t* dst = pkt_me + PKT + (size_t)tid * 3;
    pstore(dst + 0, pack3(v8[0], v8[1], v8[2], 1));
    pstore(dst + 1, pack3(v8[3], v8[4], v8[5], 1));
    pstore(dst + 2, pack3(v8[6], v8[7], 0, 1));
  }
  __syncthreads();

  const uint4* Ff4 = (const uint4*)fwf;
  float* outf = (float*)outp;
  ushort* outb = (ushort*)outp;
  const bool lw = (wid >= 5);
  const int lt = s * 3 + (wid - 5);

#pragma unroll 1
  for (int t = 0; t < SEQL; ++t) {
    const int rslot = t & 1, wslot = (t + 1) & 1, pp = (t + 1) & 1;
    const uint32_t tag = (uint32_t)(t + 1);
    const uint64_t* psrc = pkt_pt + (size_t)pp * PKT + (size_t)tid * 3;
    uint64_t p0 = pload(psrc + 0);
    uint64_t p1 = pload(psrc + 1);
    uint64_t p2 = pload(psrc + 2);

    bf16x8 a[8];
#pragma unroll
    for (int ktl = 0; ktl < 8; ++ktl)
      a[ktl] = *(const bf16x8*)&hlds[rslot][(ktl * 4 + q) * LDS_G + l15 * 8];
    int xi[4];
#pragma unroll
    for (int rgi = 0; rgi < 4; ++rgi)
      xi[rgi] = x[(size_t)((rbase + q * 4 + rgi) * SEQL + t) * xstr];
    float ew[2][4];
#pragma unroll
    for (int j = 0; j < 2; ++j) {
      int n = (nt0 + j) * 16 + l15;
#pragma unroll
      for (int rgi = 0; rgi < 4; ++rgi) ew[j][rgi] = embwb[(size_t)xi[rgi] * HID + n];
    }
    f32x4 c0 = {0.f, 0.f, 0.f, 0.f}, c1 = {0.f, 0.f, 0.f, 0.f}, lc = {0.f, 0.f, 0.f, 0.f};
#pragma unroll
    for (int ktl = 0; ktl < 8; ++ktl) {
      c0 = __builtin_amdgcn_mfma_f32_16x16x32_bf16(a[ktl], Bo[0][ktl], c0, 0, 0, 0);
      c1 = __builtin_amdgcn_mfma_f32_16x16x32_bf16(a[ktl], Bo[1][ktl], c1, 0, 0, 0);
    }
    if (lw) {
#pragma unroll
      for (int ktl = 0; ktl < 8; ++ktl) {
        bf16x8 f = *(const bf16x8*)(Ff4 + ((size_t)lt * 16 + s * 8 + ktl) * 64 + lane);
        lc = __builtin_amdgcn_mfma_f32_16x16x32_bf16(a[ktl], f, lc, 0, 0, 0);
      }
    }

    while ((uint32_t)(p0 >> 48) != tag) { __builtin_amdgcn_s_sleep(1); p0 = pload(psrc + 0); }
    while ((uint32_t)(p1 >> 48) != tag) { __builtin_amdgcn_s_sleep(1); p1 = pload(psrc + 1); }
    while ((uint32_t)(p2 >> 48) != tag) { __builtin_amdgcn_s_sleep(1); p2 = pload(psrc + 2); }
    {
      ushort w8[8] = {(ushort)p0, (ushort)(p0 >> 16), (ushort)(p0 >> 32),
                      (ushort)p1, (ushort)(p1 >> 16), (ushort)(p1 >> 32),
                      (ushort)p2, (ushort)(p2 >> 16)};
#pragma unroll
      for (int k = 0; k < 8; ++k) {
        int j = k >> 2, i = k & 3;
        int c = (2 * wid + j) * 16 + l15;
        int r = q * 4 + i;
        plds[pp][(c >> 3) * LDS_G + r * 8 + (c & 7)] = w8[k];
      }
    }
    __syncthreads();

    bf16x8 ap[8];
#pragma unroll
    for (int ktl = 0; ktl < 8; ++ktl)
      ap[ktl] = *(const bf16x8*)&plds[pp][(ktl * 4 + q) * LDS_G + l15 * 8];
#pragma unroll
    for (int ktl = 0; ktl < 8; ++ktl) {
      c0 = __builtin_amdgcn_mfma_f32_16x16x32_bf16(ap[ktl], Bp[0][ktl], c0, 0, 0, 0);
      c1 = __builtin_amdgcn_mfma_f32_16x16x32_bf16(ap[ktl], Bp[1][ktl], c1, 0, 0, 0);
    }
    if (lw) {
#pragma unroll
      for (int ktl = 0; ktl < 8; ++ktl) {
        bf16x8 f = *(const bf16x8*)(Ff4 + ((size_t)lt * 16 + (1 - s) * 8 + ktl) * 64 + lane);
        lc = __builtin_amdgcn_mfma_f32_16x16x32_bf16(ap[ktl], f, lc, 0, 0, 0);
      }
      if (t > 0) {
        int n = lt * 16 + l15;
        float bv = biasl[n];
#pragma unroll
        for (int rgi = 0; rgi < 4; ++rgi) {
          size_t idx = ((size_t)(rbase + q * 4 + rgi) * SEQL + (t - 1)) * VOC + n;
          float val = lc[rgi] + bv;
          if (MODE == 0) outb[idx] = f2bf(val); else outf[idx] = val;
        }
      }
    }

    ushort hv[8];
#pragma unroll
    for (int rgi = 0; rgi < 4; ++rgi) hv[rgi]     = f2bf(fast_tanh(c0[rgi] + ew[0][rgi]));
#pragma unroll
    for (int rgi = 0; rgi < 4; ++rgi) hv[4 + rgi] = f2bf(fast_tanh(c1[rgi] + ew[1][rgi]));
    {
      uint64_t* dst = pkt_me + (size_t)(t & 1) * PKT + (size_t)tid * 3;
      uint32_t ntag = (uint32_t)(t + 2);
      pstore(dst + 0, pack3(hv[0], hv[1], hv[2], ntag));
      pstore(dst + 1, pack3(hv[3], hv[4], hv[5], ntag));
      pstore(dst + 2, pack3(hv[6], hv[7], 0, ntag));
    }
#pragma unroll
    for (int j = 0; j < 2; ++j) {
      int nl = (2 * wid + j) * 16 + l15;
      int base = (nl >> 3) * LDS_G + (nl & 7);
#pragma unroll
      for (int rgi = 0; rgi < 4; ++rgi) hlds[wslot][base + (q * 4 + rgi) * 8] = hv[j * 4 + rgi];
    }
    __syncthreads();
  }

  {
    const uint32_t tag = (uint32_t)(SEQL + 1);
    const uint64_t* psrc = pkt_pt + PKT + (size_t)tid * 3;
    uint64_t p0 = pload(psrc + 0);
    uint64_t p1 = pload(psrc + 1);
    uint64_t p2 = pload(psrc + 2);
    while ((uint32_t)(p0 >> 48) != tag) { __builtin_amdgcn_s_sleep(1); p0 = pload(psrc + 0); }
    while ((uint32_t)(p1 >> 48) != tag) { __builtin_amdgcn_s_sleep(1); p1 = pload(psrc + 1); }
    while ((uint32_t)(p2 >> 48) != tag) { __builtin_amdgcn_s_sleep(1); p2 = pload(psrc + 2); }
    ushort w8[8] = {(ushort)p0, (ushort)(p0 >> 16), (ushort)(p0 >> 32),
                    (ushort)p1, (ushort)(p1 >> 16), (ushort)(p1 >> 32),
                    (ushort)p2, (ushort)(p2 >> 16)};
#pragma unroll
    for (int k = 0; k < 8; ++k) {
      int j = k >> 2, i = k & 3;
      int c = (2 * wid + j) * 16 + l15;
      int r = q * 4 + i;
      plds[1][(c >> 3) * LDS_G + r * 8 + (c & 7)] = w8[k];
    }
  }
  __syncthreads();
  if (lw) {
    f32x4 lc = {0.f, 0.f, 0.f, 0.f};
#pragma unroll
    for (int ktl = 0; ktl < 8; ++ktl) {
      bf16x8 av = *(const bf16x8*)&hlds[0][(ktl * 4 + q) * LDS_G + l15 * 8];
      bf16x8 f = *(const bf16x8*)(Ff4 + ((size_t)lt * 16 + s * 8 + ktl) * 64 + lane);
      lc = __builtin_amdgcn_mfma_f32_16x16x32_bf16(av, f, lc, 0, 0, 0);
    }
#pragma unroll
    for (int ktl = 0; ktl < 8; ++ktl) {
      bf16x8 av = *(const bf16x8*)&plds[1][(ktl * 4 + q) * LDS_G + l15 * 8];
      bf16x8 f = *(const bf16x8*)(Ff4 + ((size_t)lt * 16 + (1 - s) * 8 + ktl) * 64 + lane);
      lc = __builtin_amdgcn_mfma_f32_16x16x32_bf16(av, f, lc, 0, 0, 0);
    }
    int n = lt * 16 + l15;
    float bv = biasl[n];
#pragma unroll
    for (int rgi = 0; rgi < 4; ++rgi) {
      size_t idx = ((size_t)(rbase + q * 4 + rgi) * SEQL + (SEQL - 1)) * VOC + n;
      float val = lc[rgi] + bv;
      if (MODE == 0) outb[idx] = f2bf(val); else outf[idx] = val;
    }
  }
  {
    int g = tid >> 4, m = tid & 15;
    if (MODE == 0) {
      *(uint4*)&outb[(size_t)B_SZ * SEQL * VOC + (size_t)(rbase + m) * HID + s * 256 + g * 8] =
          *(const uint4*)&hlds[0][g * LDS_G + m * 8];
    } else {
      float* fh = outf + (size_t)B_SZ * SEQL * VOC;
#pragma unroll
      for (int j = 0; j < 8; ++j)
        fh[(size_t)(rbase + m) * HID + s * 256 + g * 8 + j] = bf2f(hlds[0][g * LDS_G + m * 8 + j]);
    }
  }
}

// ===================== PATH A: 8-wave producer, register-resident W =================
// Per wave: 4 nt-tiles x 16 kt = 64 frags. kt<12 in regs (48 frags = 192 VGPR,
// fits the 256/wave budget at 2 waves/SIMD), kt 12..15 in LDS (16 frags/wave,
// 128 KB total). Single h buffer (16 KB) -> LDS 144 KB.
#define RKT 12

template <int MODE>
__global__ __launch_bounds__(512, 2) void rnn_pc5(
    const int* __restrict__ x, const void* __restrict__ hiddenp,
    const float* __restrict__ embwp, const ushort* __restrict__ wf,
    const ushort* __restrict__ fwf, const void* __restrict__ fcbp,
    const int* __restrict__ flags, uint4* __restrict__ hstream,
    uint32_t* __restrict__ wm, uint32_t* __restrict__ cflag, int R,
    void* __restrict__ outp) {
  if (flags[0] != MODE) return;
  const int xstr = flags[1];
  __shared__ __align__(16) ushort lds_w[128 * 512];  // 128 KB producer W (kt 12..15)
  __shared__ __align__(16) ushort lds_h[16 * 512];   // 16 KB h (single buffer)
  const int tid = threadIdx.x;
  const int wid = tid >> 6, lane = tid & 63;
  const int q = lane >> 4, l15 = lane & 15;
  const size_t BSLV = (size_t)B_SZ * SEQL * VOC;
  const size_t SLOT16 = SLOT_U64 / 2;  // slot size in 16B units

  if (blockIdx.x < 8) {
    // ---------------- producer: 8 waves, wave owns n-tiles 4*wid..4*wid+3 ----------
    const int rg = blockIdx.x, rbase = rg * 16;
    const int hwb8 = wid * 1024 + q * 32 + (l15 >> 3) * 128 + (l15 & 7);
    const uint4* Wf4 = (const uint4*)wf;
    bf16x8 Wr[4 * RKT];
#pragma unroll
    for (int j = 0; j < 4; ++j) {
      int g = 4 * wid + j;
#pragma unroll
      for (int kt = 0; kt < 16; ++kt) {
        const uint4* s4 = Wf4 + (((size_t)g * 16 + kt) * 64 + lane);
        if (kt < RKT) {
          Wr[j * RKT + kt] = *(const bf16x8*)s4;
        } else {
          *(uint4*)&lds_w[((size_t)(wid * 4 + j) * 4 + (kt - RKT)) * 512 + lane * 8] = *s4;
        }
      }
    }
    // stage h_{-1}
#pragma unroll
    for (int k = 0; k < 16; ++k) {
      int j = k >> 2, i = k & 3;
      int r = rbase + q * 4 + i, c = (4 * wid + j) * 16 + l15;
      ushort v = (MODE == 0) ? ((const ushort*)hiddenp)[(size_t)r * HID + c]
                             : f2bf(((const float*)hiddenp)[(size_t)r * HID + c]);
      lds_h[hwb8 + (j >> 1) * 512 + (j & 1) * 256 + i * 8] = v;
    }
    __syncthreads();

    const int base16 = (wid >> 1) * 64 + q * 16 + l15;  // stream position
    const int jq = 2 * (wid & 1);                        // this wave's two quarters
    int c = 0, tloc = 0, budget = 1 << 14;
    uint4* sbase = hstream + (size_t)rg * R * SLOT16;
    uint32_t hv32[8];
#pragma unroll 1
    for (int t = 0; t < SEQL; ++t) {
      if (tloc == 0 && c) {
        if (c >= R) {  // slot reuse gate (relaxed; expected instant)
          while (budget > 0 && rload32(cflag + rg * NCHUNK + (c - R)) == 0u) {
            --budget;
            __builtin_amdgcn_s_sleep(8);
          }
        }
        sbase = hstream + ((size_t)rg * R + (size_t)(c % R)) * SLOT16;
      }
      int xi[4];
#pragma unroll
      for (int i = 0; i < 4; ++i)
        xi[i] = x[((size_t)(rbase + q * 4 + i) * SEQL + t) * xstr];
      f32x4 er[4];
      f32x4 acc[4];
#pragma unroll
      for (int j = 0; j < 4; ++j) acc[j] = (f32x4){0.f, 0.f, 0.f, 0.f};

      bf16x8 ar0 = *(const bf16x8*)&lds_h[0 * 512 + lane * 8];
      bf16x8 ar1 = *(const bf16x8*)&lds_h[1 * 512 + lane * 8];
#pragma unroll
      for (int kt = 0; kt < 16; ++kt) {
        bf16x8 acur = (kt & 1) ? ar1 : ar0;
        if (kt + 2 < 16) {
          bf16x8 nx = *(const bf16x8*)&lds_h[(kt + 2) * 512 + lane * 8];
          if (kt & 1) ar1 = nx; else ar0 = nx;
        }
        if (kt == 8) {  // xh gather: issued late (short reg liveness), used at tanh
#pragma unroll
          for (int i = 0; i < 4; ++i)
            er[i] = *(const f32x4*)(embwp + (size_t)xi[i] * HID + l15 * 32 + 4 * wid);
        }
#pragma unroll
        for (int j = 0; j < 4; ++j) {
          if (kt >= RKT) {
            bf16x8 b = *(const bf16x8*)
                &lds_w[((size_t)(wid * 4 + j) * 4 + (kt - RKT)) * 512 + lane * 8];
            acc[j] = __builtin_amdgcn_mfma_f32_16x16x32_bf16(acur, b, acc[j], 0, 0, 0);
          } else {
            acc[j] = __builtin_amdgcn_mfma_f32_16x16x32_bf16(acur, Wr[j * RKT + kt],
                                                             acc[j], 0, 0, 0);
          }
        }
      }
      // h_t = tanh(acc + xh), packed 2x bf16 per u32
#pragma unroll
      for (int j = 0; j < 4; ++j)
#pragma unroll
        for (int i2 = 0; i2 < 2; ++i2) {
          float v0 = fast_tanh(acc[j][2 * i2] + er[2 * i2][j]);
          float v1 = fast_tanh(acc[j][2 * i2 + 1] + er[2 * i2 + 1][j]);
          hv32[j * 2 + i2] = (uint32_t)f2bf(v0) | ((uint32_t)f2bf(v1) << 16);
        }
      __syncthreads();  // all A-reads of h_{t-1} done; drains publish of t-1 (vmcnt 0)
      if (tid == 0 && tloc == 0 && c) {
        __threadfence_system();          // chunk c-1 drained to L2 -> flush once
        rstore32(wm + rg, (uint32_t)t);  // t == c*CHUNK
      }
      // write h_t (lo/hi u16 extracts of packed regs)
#pragma unroll
      for (int k = 0; k < 16; ++k) {
        int j = k >> 2, i = k & 3;
        uint32_t w = hv32[j * 2 + (i >> 1)];
        lds_h[hwb8 + (j >> 1) * 512 + (j & 1) * 256 + i * 8] =
            (ushort)((i & 1) ? (w >> 16) : (w & 0xffffu));
      }
      __syncthreads();  // h_t visible
      // publish h_t (plain coalesced stores; drained at next step's first barrier)
      {
        uint4* dst = sbase + (size_t)tloc * 1024 + base16;
#pragma unroll
        for (int jh = 0; jh < 2; ++jh) {
          uint4 pv;
          pv.x = hv32[4 * jh + 0];
          pv.y = hv32[4 * jh + 1];
          pv.z = hv32[4 * jh + 2];
          pv.w = hv32[4 * jh + 3];
          dst[(size_t)(jq + jh) * 256] = pv;
        }
      }
      if (++tloc == CHUNK) { tloc = 0; ++c; }
    }
    // final hidden state (h_1023 in lds_h)
    if (tid < 256) {
      int r = tid >> 4, fk = tid & 15;
      if (MODE == 0) {
        ushort vv[32];
#pragma unroll
        for (int cc = 0; cc < 32; ++cc)
          vv[cc] = lds_h[fk * 512 + (r + ((cc >> 3) & 3) * 16) * 8 + (cc & 7)];
        ushort* o = (ushort*)outp + BSLV + (size_t)(rbase + r) * HID + fk * 32;
#pragma unroll
        for (int m = 0; m < 4; ++m) *(uint4*)(o + m * 8) = *(const uint4*)&vv[m * 8];
      } else {
        float* o = (float*)outp + BSLV + (size_t)(rbase + r) * HID + fk * 32;
#pragma unroll
        for (int cc = 0; cc < 32; ++cc)
          o[cc] = bf2f(lds_h[fk * 512 + (r + ((cc >> 3) & 3) * 16) * 8 + (cc & 7)]);
      }
    }
    __syncthreads();  // drain all stores (incl. last chunk publishes)
    if (tid == 0) {
      __threadfence_system();
      rstore32(wm + rg, (uint32_t)SEQL);
    }
  } else {
    // ---------------- consumer: one 34-step chunk of logits (round-7 proven) -------
    const int idx = (int)blockIdx.x - 8;
    const int rg = idx & 7, c = idx >> 3;
    const int rbase = rg * 16;
    const uint4* Ff4 = (const uint4*)fwf;
    const bool act = (wid < 6);  // waves 0..5 own one vocab tile each
    bf16x8 Fc[16];
#pragma unroll
    for (int kt = 0; kt < 16; ++kt)
      Fc[kt] = act ? *(const bf16x8*)(Ff4 + ((size_t)(wid * 16 + kt) * 64 + lane))
                   : (bf16x8){0, 0, 0, 0, 0, 0, 0, 0};
    float b0 = act ? ((MODE == 0) ? bf2f(((const ushort*)fcbp)[wid * 16 + l15])
                                  : ((const float*)fcbp)[wid * 16 + l15])
                   : 0.f;
    ushort* outb = (ushort*)outp;
    float* outf = (float*)outp;
    const int hwb = (tid >> 6) * 2048 + q * 32 + (l15 >> 3) * 128 + (l15 & 7);

    const int t0 = c * CHUNK;
    const int te = (t0 + CHUNK < SEQL) ? (t0 + CHUNK) : SEQL;
    int budget = 1 << 15;
    while (budget > 0 && (int)rload32(wm + rg) < te) {
      --budget;
      __builtin_amdgcn_s_sleep(32);
    }
    __threadfence_system();  // one acquire-side inv before reading the chunk
    const uint4* sb = hstream + ((size_t)rg * R + (size_t)(c % R)) * SLOT16;
#pragma unroll 1
    for (int t = t0; t < te; ++t) {
      if (tid < 256) {
        const uint4* src = sb + (size_t)(t - t0) * 1024 + tid;
        uint4 e[4];
#pragma unroll
        for (int j2 = 0; j2 < 4; ++j2) e[j2] = src[j2 * 256];
#pragma unroll
        for (int k = 0; k < 32; ++k) {
          int nt = k >> 2, i = k & 3;
          uint32_t w = ((const uint32_t*)&e[k >> 3])[(k >> 1) & 3];
          ushort v = (ushort)(w >> (16 * (k & 1)));
          lds_h[hwb + (nt >> 1) * 512 + (nt & 1) * 256 + i * 8] = v;
        }
      }
      __syncthreads();
      if (act) {
        f32x4 c0 = {0.f, 0.f, 0.f, 0.f};
#pragma unroll
        for (int kt = 0; kt < 16; ++kt) {
          bf16x8 a = *(const bf16x8*)&lds_h[kt * 512 + lane * 8];
          c0 = __builtin_amdgcn_mfma_f32_16x16x32_bf16(a, Fc[kt], c0, 0, 0, 0);
        }
#pragma unroll
        for (int i = 0; i < 4; ++i) {
          size_t row = (size_t)(rbase + q * 4 + i) * SEQL + t;
          float v0 = c0[i] + b0;
          size_t i0 = row * VOC + wid * 16 + l15;
          if (MODE == 0) outb[i0] = f2bf(v0); else outf[i0] = v0;
        }
      }
      __syncthreads();
    }
    __syncthreads();
    if (tid == 0) rstore32(cflag + rg * NCHUNK + c, 1u);
  }
}

extern "C" void kernel_launch(void* const* d_in, const int* in_sizes, int n_in,
                              void* d_out, int out_size, void* d_ws, size_t ws_size,
                              hipStream_t stream) {
  const void* x      = d_in[0];
  const void* hidden = d_in[1];
  const void* emb    = d_in[2];
  const void* wxh    = d_in[3];
  const void* whh    = d_in[4];
  const void* bh     = d_in[5];
  const void* fcw    = d_in[6];
  const void* fcb    = d_in[7];

  char* ws = (char*)d_ws;
  int*      flags  = (int*)ws;                      // 256 B
  float*    embwb  = (float*)(ws + 256);            // 196608 B (linear xh table, Path B)
  ushort*   wfrag  = (ushort*)(ws + 196864);        // 524288 B (W_hh frags)
  ushort*   fwfrag = (ushort*)(ws + 721152);        // 98304 B  (fc_w frags)

  detect_kernel<<<1, 64, 0, stream>>>((const ushort*)emb, (const int*)x, flags);

  prep_frag<0><<<128, 256, 0, stream>>>(whh, flags, wfrag, HID);
  prep_frag<1><<<128, 256, 0, stream>>>(whh, flags, wfrag, HID);
  prep_frag<0><<<24, 256, 0, stream>>>(fcw, flags, fwfrag, VOC);
  prep_frag<1><<<24, 256, 0, stream>>>(fcw, flags, fwfrag, VOC);

  // Path A layout (overlaps Path B's gbuf region; only one path runs):
  const size_t emwp_off = 819456;                   // 196608 B packed xh table
  const size_t wm_off   = 1016064;                  // 256 B
  const size_t cf_off   = 1016320;                  // 1024 B
  const size_t hs_off   = 1017344;                  // R * 4456448 B h-stream ring
  const size_t slot_all = (size_t)8 * SLOT_U64 * 8; // 4456448

  long Rl = 0;
  if (ws_size >= hs_off + 3 * slot_all) Rl = (long)((ws_size - hs_off) / slot_all);
  int R = (int)(Rl > NCHUNK ? NCHUNK : Rl);

  if (R >= 3) {
    float* embwp = (float*)(ws + emwp_off);
    uint32_t* wm = (uint32_t*)(ws + wm_off);
    uint32_t* cflag = (uint32_t*)(ws + cf_off);
    uint4* hstream = (uint4*)(ws + hs_off);
    init_sync<<<1, 256, 0, stream>>>(wm, cflag);
    prep_embw_pk<0><<<192, 256, 0, stream>>>(emb, wxh, bh, flags, embwp);
    prep_embw_pk<1><<<192, 256, 0, stream>>>(emb, wxh, bh, flags, embwp);
    rnn_pc5<0><<<8 + 8 * NCHUNK, 512, 0, stream>>>((const int*)x, hidden, embwp, wfrag,
                                                   fwfrag, fcb, flags, hstream, wm, cflag,
                                                   R, d_out);
    rnn_pc5<1><<<8 + 8 * NCHUNK, 512, 0, stream>>>((const int*)x, hidden, embwp, wfrag,
                                                   fwfrag, fcb, flags, hstream, wm, cflag,
                                                   R, d_out);
  } else if (ws_size == 0 || ws_size >= 1212672) {
    // Path B: original proven kernel (3487 us)
    uint64_t* gbuf = (uint64_t*)(ws + 819456);      // 393216 B
    prep_embw<0><<<192, 256, 0, stream>>>(emb, wxh, bh, flags, embwb);
    prep_embw<1><<<192, 256, 0, stream>>>(emb, wxh, bh, flags, embwb);
    rnn_split<0><<<16, 512, 0, stream>>>((const int*)x, hidden, embwb, wfrag, fwfrag, fcb,
                                         flags, gbuf, d_out);
    rnn_split<1><<<16, 512, 0, stream>>>((const int*)x, hidden, embwb, wfrag, fwfrag, fcb,
                                         flags, gbuf, d_out);
  }
}